// Round 5
// baseline (1087.846 us; speedup 1.0000x reference)
//
#include <hip/hip_runtime.h>
#include <hip/hip_bf16.h>

// Shapes (fixed): B=128, F=8, K=256, D=256, H=256, HFF=512, L=2, M_PREV=2
#define B_   128
#define F_   8
#define K_   256
#define D_   256
#define H_   256
#define HFF_ 512
#define RT   32   // k-rows per block in main kernel

typedef short short8 __attribute__((ext_vector_type(8)));    // bf16x8 MFMA frag
typedef short short4v __attribute__((ext_vector_type(4)));   // packed 4x bf16
typedef float floatx4 __attribute__((ext_vector_type(4)));   // MFMA acc

#define MFMA(a,b,c) __builtin_amdgcn_mfma_f32_16x16x32_bf16(a,b,c,0,0,0)

__device__ inline short bf16_rne(float x) {
  union { float f; unsigned u; } v; v.f = x;
  unsigned r = v.u + 0x7fff + ((v.u >> 16) & 1);
  return (short)(r >> 16);
}
__device__ inline float bf16_to_f(short s) {
  union { float f; unsigned u; } v; v.u = ((unsigned)(unsigned short)s) << 16;
  return v.f;
}
// hi/lo split via the HIP header converts (RNE; compiles to the HW cvt path)
__device__ inline void splitf(float x, short& hi, short& lo) {
  __hip_bfloat16 h = __float2bfloat16(x);
  float hf = __bfloat162float(h);
  __hip_bfloat16 l = __float2bfloat16(x - hf);
  hi = __builtin_bit_cast(short, h);
  lo = __builtin_bit_cast(short, l);
}

// ---------------------------------------------------------------------------
__global__ void k_h0(const float* __restrict__ cb, const float* __restrict__ Win,
                     const float* __restrict__ bin, float* __restrict__ h0) {
  __shared__ float row[D_];
  const int k = blockIdx.x, j = threadIdx.x;
  row[j] = cb[k * D_ + j];
  __syncthreads();
  float acc = bin[j];
  #pragma unroll 4
  for (int i = 0; i < D_; ++i) acc = fmaf(row[i], Win[i * H_ + j], acc);
  h0[k * H_ + j] = acc;
}

__global__ void k_uv(const float* __restrict__ h0, const float* __restrict__ Wcat,
                     const float* __restrict__ bcat, const float* __restrict__ xhat,
                     float* __restrict__ u, float* __restrict__ v) {
  __shared__ float row[D_];
  const int blk = blockIdx.x, j = threadIdx.x;
  if (blk < K_) {
    row[j] = h0[blk * H_ + j];
    __syncthreads();
    float acc = 0.f;
    #pragma unroll 4
    for (int i = 0; i < H_; ++i) acc = fmaf(row[i], Wcat[i * H_ + j], acc);
    u[blk * H_ + j] = acc;
  } else {
    const int bf = blk - K_;
    row[j] = xhat[bf * D_ + j];
    __syncthreads();
    float acc = bcat[j];
    #pragma unroll 4
    for (int i = 0; i < D_; ++i) acc = fmaf(row[i], Wcat[(H_ + i) * H_ + j], acc);
    v[bf * H_ + j] = acc;
  }
}

// ---------------------------------------------------------------------------
// Pre-shuffle a weight matrix [K x N] into MFMA fragment order, bf16 hi/lo.
// (A and B lane layouts coincide for 16x16x32, so these frags serve as the
//  A-operand of the transposed GEMMs: element (m=ntile*16+lane&15,
//  k=kstep*32+(lane>>4)*8+jj).)
__global__ void k_wfrag(const float* __restrict__ src, short* __restrict__ dhi,
                        short* __restrict__ dlo, int N, int NT) {
  const int e = blockIdx.x * 256 + threadIdx.x;
  const int jj = e & 7, lane = (e >> 3) & 63, r = e >> 9;
  const int ntile = r % NT, kstep = r / NT;
  const int row = kstep * 32 + (lane >> 4) * 8 + jj;
  const int colc = ntile * 16 + (lane & 15);
  const float val = src[row * N + colc];
  const short hi = bf16_rne(val);
  dhi[e] = hi;
  dlo[e] = bf16_rne(val - bf16_to_f(hi));
}

// ---------------------------------------------------------------------------
// MFMA main kernel (transposed form): C' = W^T @ h^T. Weight frags are the
// A-operand, h/hm frags (read from LDS row-major) are the B-operand.
// C-layout gives each lane 4 CONSECUTIVE output features -> packed epilogues.
__global__ __launch_bounds__(256, 3) void k_main(
    const float* __restrict__ u, const float* __restrict__ v,
    const short* __restrict__ w1h, const short* __restrict__ w1l,
    const float* __restrict__ b1,
    const short* __restrict__ w2h, const short* __restrict__ w2l,
    const float* __restrict__ b2,
    const short* __restrict__ wouth, const short* __restrict__ woutl,
    const float* __restrict__ bout,
    const float* __restrict__ cb, const float* __restrict__ xhat,
    const float* __restrict__ x, float* __restrict__ dists) {
  __shared__ short hA_hi[32][264];    // [candidate row][feature], stride 132 dw
  __shared__ short hA_lo[32][264];
  __shared__ short hmA_hi[32][136];   // [row][chunk-local feature]
  __shared__ short hmA_lo[32][136];
  __shared__ float x_s[D_], xh_s[D_];
  __shared__ float dist_s[4][32];

  const int t = threadIdx.x;
  const int blk = blockIdx.x;
  const int bf = blk >> 3, k0 = (blk & 7) << 5;
  const int b = bf >> 3, f = bf & 7;
  const int wave = t >> 6, lane = t & 63;
  const int col = lane & 15, quad = lane >> 4;
  const int lane8 = lane * 8;

  x_s[t]  = x[b * D_ + t];
  xh_s[t] = xhat[bf * D_ + t];

  // stage h = u + v, split into bf16 hi/lo, packed b128 writes
  {
    const int r = t >> 3, c0 = (t & 7) * 32;
    const float* up = u + (k0 + r) * H_ + c0;
    const float* vp = v + bf * H_ + c0;
    #pragma unroll
    for (int j = 0; j < 32; j += 8) {
      float4 uA = *(const float4*)(up + j);
      float4 vA = *(const float4*)(vp + j);
      float4 uB = *(const float4*)(up + j + 4);
      float4 vB = *(const float4*)(vp + j + 4);
      float hv[8] = {uA.x + vA.x, uA.y + vA.y, uA.z + vA.z, uA.w + vA.w,
                     uB.x + vB.x, uB.y + vB.y, uB.z + vB.z, uB.w + vB.w};
      short8 hi8, lo8;
      #pragma unroll
      for (int q = 0; q < 8; ++q) {
        short th, tl; splitf(hv[q], th, tl);
        hi8[q] = th; lo8[q] = tl;
      }
      *(short8*)&hA_hi[r][c0 + j] = hi8;
      *(short8*)&hA_lo[r][c0 + j] = lo8;
    }
  }
  __syncthreads();

  const floatx4 zero4 = {0.f, 0.f, 0.f, 0.f};

  #pragma unroll 1
  for (int l = 0; l < 2; ++l) {
    const short* w1h_l = w1h + l * (H_ * HFF_);
    const short* w1l_l = w1l + l * (H_ * HFF_);
    const short* w2h_l = w2h + l * (HFF_ * H_);
    const short* w2l_l = w2l + l * (HFF_ * H_);
    const float* b1l = b1 + l * HFF_;
    const float* b2l = b2 + l * H_;

    floatx4 acc2[4][2];   // [out-feature tile][row tile]
    #pragma unroll
    for (int mt = 0; mt < 4; ++mt)
      #pragma unroll
      for (int nt = 0; nt < 2; ++nt) acc2[mt][nt] = zero4;

    #pragma unroll 1
    for (int ch = 0; ch < 4; ++ch) {
      // ---- GEMM1': hm' = relu(W1[:,chunk]^T @ h^T + b1) ----
      floatx4 acc1[2][2];
      #pragma unroll
      for (int mt = 0; mt < 2; ++mt)
        #pragma unroll
        for (int nt = 0; nt < 2; ++nt) acc1[mt][nt] = zero4;

      const short* w1h_b = w1h_l + (ch * 8 + wave * 2) * 512 + lane8;
      const short* w1l_b = w1l_l + (ch * 8 + wave * 2) * 512 + lane8;

      #pragma unroll 2
      for (int ks = 0; ks < 8; ++ks) {
        short8 bh0 = *(const short8*)&hA_hi[col][ks * 32 + quad * 8];
        short8 bl0 = *(const short8*)&hA_lo[col][ks * 32 + quad * 8];
        short8 bh1 = *(const short8*)&hA_hi[16 + col][ks * 32 + quad * 8];
        short8 bl1 = *(const short8*)&hA_lo[16 + col][ks * 32 + quad * 8];
        const int ko = ks * 32 * 512;
        #pragma unroll
        for (int mt = 0; mt < 2; ++mt) {
          const int off = ko + mt * 512;
          short8 awh = *(const short8*)(w1h_b + off);
          short8 awl = *(const short8*)(w1l_b + off);
          acc1[mt][0] = MFMA(awh, bh0, acc1[mt][0]);
          acc1[mt][0] = MFMA(awl, bh0, acc1[mt][0]);
          acc1[mt][0] = MFMA(awh, bl0, acc1[mt][0]);
          acc1[mt][1] = MFMA(awh, bh1, acc1[mt][1]);
          acc1[mt][1] = MFMA(awl, bh1, acc1[mt][1]);
          acc1[mt][1] = MFMA(awh, bl1, acc1[mt][1]);
        }
      }
      // bias + relu + split, packed b64 stores (4 consecutive features/lane)
      #pragma unroll
      for (int mt = 0; mt < 2; ++mt) {
        const int floc = (wave * 2 + mt) * 16 + quad * 4;
        float4 bb = *(const float4*)&b1l[ch * 128 + floc];
        #pragma unroll
        for (int nt = 0; nt < 2; ++nt) {
          const int row = nt * 16 + col;
          short4v nh, nl;
          #pragma unroll
          for (int p = 0; p < 4; ++p) {
            float hm = fmaxf(acc1[mt][nt][p] + ((const float*)&bb)[p], 0.f);
            short th, tl; splitf(hm, th, tl);
            nh[p] = th; nl[p] = tl;
          }
          *(short4v*)&hmA_hi[row][floc] = nh;
          *(short4v*)&hmA_lo[row][floc] = nl;
        }
      }
      __syncthreads();

      // ---- GEMM2': acc2 += W2[chunk,:]^T @ hm'^T ----
      const short* w2h_b = w2h_l + (ch * 64 + wave * 4) * 512 + lane8;
      const short* w2l_b = w2l_l + (ch * 64 + wave * 4) * 512 + lane8;
      #pragma unroll 2
      for (int ks = 0; ks < 4; ++ks) {
        short8 bh0 = *(const short8*)&hmA_hi[col][ks * 32 + quad * 8];
        short8 bl0 = *(const short8*)&hmA_lo[col][ks * 32 + quad * 8];
        short8 bh1 = *(const short8*)&hmA_hi[16 + col][ks * 32 + quad * 8];
        short8 bl1 = *(const short8*)&hmA_lo[16 + col][ks * 32 + quad * 8];
        const int ko = ks * 16 * 512;
        #pragma unroll
        for (int mt = 0; mt < 4; ++mt) {
          const int off = ko + mt * 512;
          short8 awh = *(const short8*)(w2h_b + off);
          short8 awl = *(const short8*)(w2l_b + off);
          acc2[mt][0] = MFMA(awh, bh0, acc2[mt][0]);
          acc2[mt][0] = MFMA(awl, bh0, acc2[mt][0]);
          acc2[mt][0] = MFMA(awh, bl0, acc2[mt][0]);
          acc2[mt][1] = MFMA(awh, bh1, acc2[mt][1]);
          acc2[mt][1] = MFMA(awl, bh1, acc2[mt][1]);
          acc2[mt][1] = MFMA(awh, bl1, acc2[mt][1]);
        }
      }
      __syncthreads();
    }

    // ---- residual: h += acc2 + b2, packed b64 read/modify/write ----
    #pragma unroll
    for (int mt = 0; mt < 4; ++mt) {
      const int feat0 = (wave * 4 + mt) * 16 + quad * 4;
      float4 bb = *(const float4*)&b2l[feat0];
      #pragma unroll
      for (int nt = 0; nt < 2; ++nt) {
        const int row = nt * 16 + col;
        short4v oh = *(short4v*)&hA_hi[row][feat0];
        short4v ol = *(short4v*)&hA_lo[row][feat0];
        short4v nh, nl;
        #pragma unroll
        for (int p = 0; p < 4; ++p) {
          float hold = bf16_to_f(oh[p]) + bf16_to_f(ol[p]);
          float hnew = hold + acc2[mt][nt][p] + ((const float*)&bb)[p];
          short th, tl; splitf(hnew, th, tl);
          nh[p] = th; nl[p] = tl;
        }
        *(short4v*)&hA_hi[row][feat0] = nh;
        *(short4v*)&hA_lo[row][feat0] = nl;
      }
    }
    __syncthreads();
  }

  // ---- GEMM3': cw' = Wout^T @ h^T (+bout+cb+xhat), then distance ----
  floatx4 acc3[4][2];
  #pragma unroll
  for (int mt = 0; mt < 4; ++mt)
    #pragma unroll
    for (int nt = 0; nt < 2; ++nt) acc3[mt][nt] = zero4;

  const short* woh_b = wouth + (wave * 4) * 512 + lane8;
  const short* wol_b = woutl + (wave * 4) * 512 + lane8;
  #pragma unroll 2
  for (int ks = 0; ks < 8; ++ks) {
    short8 bh0 = *(const short8*)&hA_hi[col][ks * 32 + quad * 8];
    short8 bl0 = *(const short8*)&hA_lo[col][ks * 32 + quad * 8];
    short8 bh1 = *(const short8*)&hA_hi[16 + col][ks * 32 + quad * 8];
    short8 bl1 = *(const short8*)&hA_lo[16 + col][ks * 32 + quad * 8];
    const int ko = ks * 16 * 512;
    #pragma unroll
    for (int mt = 0; mt < 4; ++mt) {
      const int off = ko + mt * 512;
      short8 awh = *(const short8*)(woh_b + off);
      short8 awl = *(const short8*)(wol_b + off);
      acc3[mt][0] = MFMA(awh, bh0, acc3[mt][0]);
      acc3[mt][0] = MFMA(awl, bh0, acc3[mt][0]);
      acc3[mt][0] = MFMA(awh, bl0, acc3[mt][0]);
      acc3[mt][1] = MFMA(awh, bh1, acc3[mt][1]);
      acc3[mt][1] = MFMA(awl, bh1, acc3[mt][1]);
      acc3[mt][1] = MFMA(awh, bl1, acc3[mt][1]);
    }
  }

  float s0 = 0.f, s1 = 0.f;
  const float* cbr0 = cb + (k0 + col) * D_;
  const float* cbr1 = cb + (k0 + 16 + col) * D_;
  #pragma unroll
  for (int mt = 0; mt < 4; ++mt) {
    const int d0 = (wave * 4 + mt) * 16 + quad * 4;
    float4 bo = *(const float4*)&bout[d0];
    float4 xv = *(const float4*)&x_s[d0];
    float4 xh = *(const float4*)&xh_s[d0];
    float4 c0 = *(const float4*)&cbr0[d0];
    float4 c1 = *(const float4*)&cbr1[d0];
    #pragma unroll
    for (int p = 0; p < 4; ++p) {
      float base = ((const float*)&bo)[p] + ((const float*)&xh)[p];
      float xx = ((const float*)&xv)[p];
      float cw0 = acc3[mt][0][p] + base + ((const float*)&c0)[p];
      s0 += cw0 * (cw0 - 2.f * xx);   // -||x||^2 const: argmin-invariant
      float cw1 = acc3[mt][1][p] + base + ((const float*)&c1)[p];
      s1 += cw1 * (cw1 - 2.f * xx);
    }
  }
  s0 += __shfl_xor(s0, 16, 64); s0 += __shfl_xor(s0, 32, 64);
  s1 += __shfl_xor(s1, 16, 64); s1 += __shfl_xor(s1, 32, 64);
  if (quad == 0) {
    dist_s[wave][col] = s0;
    dist_s[wave][16 + col] = s1;
  }
  __syncthreads();
  if (t < 32) {
    float d = dist_s[0][t] + dist_s[1][t] + dist_s[2][t] + dist_s[3][t];
    dists[b * (F_ * K_) + f * K_ + k0 + t] = d;
  }
}

// ---------------------------------------------------------------------------
// Top-8 candidates per b from approx dists (iterative selection).
__global__ void k_top8(const float* __restrict__ dists, int* __restrict__ topi) {
  __shared__ float ds[F_ * K_];
  __shared__ float bv[256];
  __shared__ int bi_s[256];
  const int b = blockIdx.x, t = threadIdx.x;
  for (int j = t; j < F_ * K_; j += 256) ds[j] = dists[b * (F_ * K_) + j];
  __syncthreads();
  for (int pass = 0; pass < 8; ++pass) {
    float best = 3.4e38f; int bi = 0;
    for (int j = t; j < F_ * K_; j += 256) {
      const float dv = ds[j];
      if (dv < best) { best = dv; bi = j; }
    }
    bv[t] = best; bi_s[t] = bi;
    __syncthreads();
    for (int s = 128; s > 0; s >>= 1) {
      if (t < s) {
        const float ov = bv[t + s]; const int oi = bi_s[t + s];
        if (ov < bv[t] || (ov == bv[t] && oi < bi_s[t])) { bv[t] = ov; bi_s[t] = oi; }
      }
      __syncthreads();
    }
    if (t == 0) { topi[b * 8 + pass] = bi_s[0]; ds[bi_s[0]] = 3.4e38f; }
    __syncthreads();
  }
}

// ---------------------------------------------------------------------------
// Exact fp32 rescore of one candidate row per block (same math as R2 pass).
__global__ void k_rescore(const float* __restrict__ u, const float* __restrict__ v,
                          const float* __restrict__ W1, const float* __restrict__ b1,
                          const float* __restrict__ W2, const float* __restrict__ b2,
                          const float* __restrict__ Wout, const float* __restrict__ bout,
                          const float* __restrict__ cb, const float* __restrict__ xhat,
                          const float* __restrict__ x, const int* __restrict__ topi,
                          float* __restrict__ resc) {
  __shared__ float hs[H_];
  __shared__ float hms[HFF_];
  __shared__ float red[256];
  const int bc = blockIdx.x, t = threadIdx.x;
  const int b = bc >> 3;
  const int idx = topi[bc];
  const int f = idx >> 8, k = idx & 255;
  const int bf = b * F_ + f;

  hs[t] = u[k * H_ + t] + v[bf * H_ + t];
  __syncthreads();
  for (int l = 0; l < 2; ++l) {
    const float* W1l = W1 + l * (H_ * HFF_);
    const float* W2l = W2 + l * (HFF_ * H_);
    float a0 = b1[l * HFF_ + t], a1 = b1[l * HFF_ + 256 + t];
    for (int i = 0; i < H_; ++i) {
      const float hv = hs[i];
      a0 = fmaf(hv, W1l[i * HFF_ + t], a0);
      a1 = fmaf(hv, W1l[i * HFF_ + 256 + t], a1);
    }
    hms[t] = fmaxf(a0, 0.f);
    hms[t + 256] = fmaxf(a1, 0.f);
    __syncthreads();
    float hn = hs[t] + b2[l * H_ + t];
    for (int jj = 0; jj < HFF_; ++jj)
      hn = fmaf(hms[jj], W2l[jj * H_ + t], hn);
    __syncthreads();
    hs[t] = hn;
    __syncthreads();
  }
  float cw = bout[t] + cb[k * D_ + t] + xhat[bf * D_ + t];
  for (int i = 0; i < H_; ++i) cw = fmaf(hs[i], Wout[i * D_ + t], cw);
  red[t] = cw * (cw - 2.f * x[b * D_ + t]);
  __syncthreads();
  for (int s = 128; s > 0; s >>= 1) {
    if (t < s) red[t] += red[t + s];
    __syncthreads();
  }
  if (t == 0) resc[bc] = red[0];
}

// ---------------------------------------------------------------------------
// Pick exact argmin among 8 rescored candidates; recompute winner; write out.
__global__ void k_final(const float* __restrict__ u, const float* __restrict__ v,
                        const float* __restrict__ W1, const float* __restrict__ b1,
                        const float* __restrict__ W2, const float* __restrict__ b2,
                        const float* __restrict__ Wout, const float* __restrict__ bout,
                        const float* __restrict__ cb, const float* __restrict__ xhat,
                        const int* __restrict__ codes, const int* __restrict__ topi,
                        const float* __restrict__ resc, float* __restrict__ out) {
  __shared__ float hs[H_];
  __shared__ float hms[HFF_];
  __shared__ int idx_sh;
  const int b = blockIdx.x, t = threadIdx.x;
  if (t == 0) {
    float bd = 3.4e38f; int bidx = 1 << 30;
    for (int c = 0; c < 8; ++c) {
      const float d = resc[b * 8 + c];
      const int ix = topi[b * 8 + c];
      if (d < bd || (d == bd && ix < bidx)) { bd = d; bidx = ix; }
    }
    idx_sh = bidx;
  }
  __syncthreads();
  const int idx = idx_sh;
  const int f = idx >> 8, k = idx & 255;
  const int bf = b * F_ + f;

  hs[t] = u[k * H_ + t] + v[bf * H_ + t];
  __syncthreads();
  for (int l = 0; l < 2; ++l) {
    const float* W1l = W1 + l * (H_ * HFF_);
    const float* W2l = W2 + l * (HFF_ * H_);
    float a0 = b1[l * HFF_ + t], a1 = b1[l * HFF_ + 256 + t];
    for (int i = 0; i < H_; ++i) {
      const float hv = hs[i];
      a0 = fmaf(hv, W1l[i * HFF_ + t], a0);
      a1 = fmaf(hv, W1l[i * HFF_ + 256 + t], a1);
    }
    hms[t] = fmaxf(a0, 0.f);
    hms[t + 256] = fmaxf(a1, 0.f);
    __syncthreads();
    float hn = hs[t] + b2[l * H_ + t];
    for (int jj = 0; jj < HFF_; ++jj)
      hn = fmaf(hms[jj], W2l[jj * H_ + t], hn);
    __syncthreads();
    hs[t] = hn;
    __syncthreads();
  }
  float cw = bout[t] + cb[k * D_ + t] + xhat[bf * D_ + t];
  for (int i = 0; i < H_; ++i) cw = fmaf(hs[i], Wout[i * D_ + t], cw);

  out[b * D_ + t] = cw;
  if (t < 2)
    out[B_ * D_ + t * B_ + b] = (float)codes[t * B_ + b];
  else if (t == 2)
    out[B_ * D_ + 2 * B_ + b] = (float)idx;
}

// ---------------------------------------------------------------------------
extern "C" void kernel_launch(void* const* d_in, const int* in_sizes, int n_in,
                              void* d_out, int out_size, void* d_ws, size_t ws_size,
                              hipStream_t stream) {
  const float* x    = (const float*)d_in[0];
  const float* xhat = (const float*)d_in[1];
  const int*   codes= (const int*)d_in[2];
  const float* cb   = (const float*)d_in[3];
  const float* Win  = (const float*)d_in[4];
  const float* bin  = (const float*)d_in[5];
  const float* Wcat = (const float*)d_in[6];
  const float* bcat = (const float*)d_in[7];
  const float* W1   = (const float*)d_in[8];
  const float* b1   = (const float*)d_in[9];
  const float* W2   = (const float*)d_in[10];
  const float* b2   = (const float*)d_in[11];
  const float* Wout = (const float*)d_in[12];
  const float* bout = (const float*)d_in[13];
  float* out = (float*)d_out;

  float* h0    = (float*)d_ws;                  // 65536 f
  float* u     = h0 + K_ * H_;                  // 65536 f
  float* v     = u + K_ * H_;                   // 262144 f
  float* dists = v + B_ * F_ * H_;              // 262144 f
  float* resc  = dists + B_ * F_ * K_;          // 1024 f
  int*   topi  = (int*)(resc + 1024);           // 1024 i
  int*   pad   = topi + 1024;                   // 128 pad (keeps 16B align)
  short* w1h   = (short*)(pad + 128);           // 262144 sh
  short* w1l   = w1h + 2 * H_ * HFF_;
  short* w2h   = w1l + 2 * H_ * HFF_;
  short* w2l   = w2h + 2 * HFF_ * H_;
  short* wouth = w2l + 2 * HFF_ * H_;
  short* woutl = wouth + H_ * D_;

  k_h0<<<K_, 256, 0, stream>>>(cb, Win, bin, h0);
  k_uv<<<K_ + B_ * F_, 256, 0, stream>>>(h0, Wcat, bcat, xhat, u, v);
  k_wfrag<<<512, 256, 0, stream>>>(W1, w1h, w1l, HFF_, 32);
  k_wfrag<<<512, 256, 0, stream>>>(W1 + H_ * HFF_, w1h + H_ * HFF_, w1l + H_ * HFF_, HFF_, 32);
  k_wfrag<<<512, 256, 0, stream>>>(W2, w2h, w2l, H_, 16);
  k_wfrag<<<512, 256, 0, stream>>>(W2 + HFF_ * H_, w2h + HFF_ * H_, w2l + HFF_ * H_, H_, 16);
  k_wfrag<<<256, 256, 0, stream>>>(Wout, wouth, woutl, D_, 16);

  k_main<<<B_ * F_ * (K_ / RT), 256, 0, stream>>>(u, v, w1h, w1l, b1, w2h, w2l, b2,
                                                  wouth, woutl, bout, cb, xhat, x, dists);
  k_top8<<<B_, 256, 0, stream>>>(dists, topi);
  k_rescore<<<B_ * 8, 256, 0, stream>>>(u, v, W1, b1, W2, b2, Wout, bout, cb, xhat,
                                        x, topi, resc);
  k_final<<<B_, 256, 0, stream>>>(u, v, W1, b1, W2, b2, Wout, bout, cb, xhat,
                                  codes, topi, resc, out);
}

// Round 6
// 806.853 us; speedup vs baseline: 1.3483x; 1.3483x over previous
//
#include <hip/hip_runtime.h>
#include <hip/hip_bf16.h>

// Shapes (fixed): B=128, F=8, K=256, D=256, H=256, HFF=512, L=2, M_PREV=2
#define B_   128
#define F_   8
#define K_   256
#define D_   256
#define H_   256
#define HFF_ 512
#define RT   32   // k-rows per block in main kernel

typedef short short8 __attribute__((ext_vector_type(8)));    // bf16x8 MFMA frag
typedef short short4v __attribute__((ext_vector_type(4)));   // packed 4x bf16
typedef float floatx4 __attribute__((ext_vector_type(4)));   // MFMA acc

#define MFMA(a,b,c) __builtin_amdgcn_mfma_f32_16x16x32_bf16(a,b,c,0,0,0)

__device__ inline short bf16_rne(float x) {
  union { float f; unsigned u; } v; v.f = x;
  unsigned r = v.u + 0x7fff + ((v.u >> 16) & 1);
  return (short)(r >> 16);
}
__device__ inline float bf16_to_f(short s) {
  union { float f; unsigned u; } v; v.u = ((unsigned)(unsigned short)s) << 16;
  return v.f;
}
__device__ inline void splitf(float x, short& hi, short& lo) {
  __hip_bfloat16 h = __float2bfloat16(x);
  float hf = __bfloat162float(h);
  __hip_bfloat16 l = __float2bfloat16(x - hf);
  hi = __builtin_bit_cast(short, h);
  lo = __builtin_bit_cast(short, l);
}

// ---------------------------------------------------------------------------
__global__ void k_h0(const float* __restrict__ cb, const float* __restrict__ Win,
                     const float* __restrict__ bin, float* __restrict__ h0) {
  __shared__ float row[D_];
  const int k = blockIdx.x, j = threadIdx.x;
  row[j] = cb[k * D_ + j];
  __syncthreads();
  float acc = bin[j];
  #pragma unroll 4
  for (int i = 0; i < D_; ++i) acc = fmaf(row[i], Win[i * H_ + j], acc);
  h0[k * H_ + j] = acc;
}

__global__ void k_uv(const float* __restrict__ h0, const float* __restrict__ Wcat,
                     const float* __restrict__ bcat, const float* __restrict__ xhat,
                     float* __restrict__ u, float* __restrict__ v) {
  __shared__ float row[D_];
  const int blk = blockIdx.x, j = threadIdx.x;
  if (blk < K_) {
    row[j] = h0[blk * H_ + j];
    __syncthreads();
    float acc = 0.f;
    #pragma unroll 4
    for (int i = 0; i < H_; ++i) acc = fmaf(row[i], Wcat[i * H_ + j], acc);
    u[blk * H_ + j] = acc;
  } else {
    const int bf = blk - K_;
    row[j] = xhat[bf * D_ + j];
    __syncthreads();
    float acc = bcat[j];
    #pragma unroll 4
    for (int i = 0; i < D_; ++i) acc = fmaf(row[i], Wcat[(H_ + i) * H_ + j], acc);
    v[bf * H_ + j] = acc;
  }
}

// ---------------------------------------------------------------------------
// Pre-shuffle a weight matrix [K x N] into MFMA fragment order, bf16 hi/lo.
__global__ void k_wfrag(const float* __restrict__ src, short* __restrict__ dhi,
                        short* __restrict__ dlo, int N, int NT) {
  const int e = blockIdx.x * 256 + threadIdx.x;
  const int jj = e & 7, lane = (e >> 3) & 63, r = e >> 9;
  const int ntile = r % NT, kstep = r / NT;
  const int row = kstep * 32 + (lane >> 4) * 8 + jj;
  const int colc = ntile * 16 + (lane & 15);
  const float val = src[row * N + colc];
  const short hi = bf16_rne(val);
  dhi[e] = hi;
  dlo[e] = bf16_rne(val - bf16_to_f(hi));
}

// ---------------------------------------------------------------------------
// MFMA main kernel (transposed form): C' = W^T @ h^T. Weight frags = A-operand
// (bf16 HI only — R6: 2-term split Wh*hh + Wh*hl halves L2 weight traffic and
// cuts MFMA count to 2/3; h keeps hi/lo in LDS; top-8 exact rescore absorbs
// the extra approx error). h/hm frags from LDS = B-operand.
__global__ __launch_bounds__(256, 3) void k_main(
    const float* __restrict__ u, const float* __restrict__ v,
    const short* __restrict__ w1h, const short* __restrict__ w1l,
    const float* __restrict__ b1,
    const short* __restrict__ w2h, const short* __restrict__ w2l,
    const float* __restrict__ b2,
    const short* __restrict__ wouth, const short* __restrict__ woutl,
    const float* __restrict__ bout,
    const float* __restrict__ cb, const float* __restrict__ xhat,
    const float* __restrict__ x, float* __restrict__ dists) {
  __shared__ short hA_hi[32][264];    // [candidate row][feature]
  __shared__ short hA_lo[32][264];
  __shared__ short hmA_hi[32][136];   // [row][chunk-local feature]
  __shared__ short hmA_lo[32][136];
  __shared__ float x_s[D_], xh_s[D_];
  __shared__ float dist_s[4][32];

  const int t = threadIdx.x;
  const int blk = blockIdx.x;
  const int bf = blk >> 3, k0 = (blk & 7) << 5;
  const int b = bf >> 3, f = bf & 7;
  const int wave = t >> 6, lane = t & 63;
  const int col = lane & 15, quad = lane >> 4;
  const int lane8 = lane * 8;

  x_s[t]  = x[b * D_ + t];
  xh_s[t] = xhat[bf * D_ + t];

  // stage h = u + v, split into bf16 hi/lo, packed b128 writes
  {
    const int r = t >> 3, c0 = (t & 7) * 32;
    const float* up = u + (k0 + r) * H_ + c0;
    const float* vp = v + bf * H_ + c0;
    #pragma unroll
    for (int j = 0; j < 32; j += 8) {
      float4 uA = *(const float4*)(up + j);
      float4 vA = *(const float4*)(vp + j);
      float4 uB = *(const float4*)(up + j + 4);
      float4 vB = *(const float4*)(vp + j + 4);
      float hv[8] = {uA.x + vA.x, uA.y + vA.y, uA.z + vA.z, uA.w + vA.w,
                     uB.x + vB.x, uB.y + vB.y, uB.z + vB.z, uB.w + vB.w};
      short8 hi8, lo8;
      #pragma unroll
      for (int q = 0; q < 8; ++q) {
        short th, tl; splitf(hv[q], th, tl);
        hi8[q] = th; lo8[q] = tl;
      }
      *(short8*)&hA_hi[r][c0 + j] = hi8;
      *(short8*)&hA_lo[r][c0 + j] = lo8;
    }
  }
  __syncthreads();

  const floatx4 zero4 = {0.f, 0.f, 0.f, 0.f};

  #pragma unroll 1
  for (int l = 0; l < 2; ++l) {
    const short* w1h_l = w1h + l * (H_ * HFF_);
    const short* w2h_l = w2h + l * (HFF_ * H_);
    const float* b1l = b1 + l * HFF_;
    const float* b2l = b2 + l * H_;

    floatx4 acc2[4][2];   // [out-feature tile][row tile]
    #pragma unroll
    for (int mt = 0; mt < 4; ++mt)
      #pragma unroll
      for (int nt = 0; nt < 2; ++nt) acc2[mt][nt] = zero4;

    #pragma unroll 1
    for (int ch = 0; ch < 4; ++ch) {
      // ---- GEMM1': hm' = relu(W1[:,chunk]^T @ h^T + b1) ----
      floatx4 acc1[2][2];
      #pragma unroll
      for (int mt = 0; mt < 2; ++mt)
        #pragma unroll
        for (int nt = 0; nt < 2; ++nt) acc1[mt][nt] = zero4;

      const short* w1h_b = w1h_l + (ch * 8 + wave * 2) * 512 + lane8;

      #pragma unroll 2
      for (int ks = 0; ks < 8; ++ks) {
        short8 bh0 = *(const short8*)&hA_hi[col][ks * 32 + quad * 8];
        short8 bl0 = *(const short8*)&hA_lo[col][ks * 32 + quad * 8];
        short8 bh1 = *(const short8*)&hA_hi[16 + col][ks * 32 + quad * 8];
        short8 bl1 = *(const short8*)&hA_lo[16 + col][ks * 32 + quad * 8];
        const int ko = ks * 32 * 512;
        #pragma unroll
        for (int mt = 0; mt < 2; ++mt) {
          short8 awh = *(const short8*)(w1h_b + ko + mt * 512);
          acc1[mt][0] = MFMA(awh, bh0, acc1[mt][0]);
          acc1[mt][0] = MFMA(awh, bl0, acc1[mt][0]);
          acc1[mt][1] = MFMA(awh, bh1, acc1[mt][1]);
          acc1[mt][1] = MFMA(awh, bl1, acc1[mt][1]);
        }
      }
      // bias + relu + split, packed b64 stores (4 consecutive features/lane)
      #pragma unroll
      for (int mt = 0; mt < 2; ++mt) {
        const int floc = (wave * 2 + mt) * 16 + quad * 4;
        float4 bb = *(const float4*)&b1l[ch * 128 + floc];
        #pragma unroll
        for (int nt = 0; nt < 2; ++nt) {
          const int row = nt * 16 + col;
          short4v nh, nl;
          #pragma unroll
          for (int p = 0; p < 4; ++p) {
            float hm = fmaxf(acc1[mt][nt][p] + ((const float*)&bb)[p], 0.f);
            short th, tl; splitf(hm, th, tl);
            nh[p] = th; nl[p] = tl;
          }
          *(short4v*)&hmA_hi[row][floc] = nh;
          *(short4v*)&hmA_lo[row][floc] = nl;
        }
      }
      __syncthreads();

      // ---- GEMM2': acc2 += W2[chunk,:]^T @ hm'^T ----
      const short* w2h_b = w2h_l + (ch * 64 + wave * 4) * 512 + lane8;
      #pragma unroll 2
      for (int ks = 0; ks < 4; ++ks) {
        short8 bh0 = *(const short8*)&hmA_hi[col][ks * 32 + quad * 8];
        short8 bl0 = *(const short8*)&hmA_lo[col][ks * 32 + quad * 8];
        short8 bh1 = *(const short8*)&hmA_hi[16 + col][ks * 32 + quad * 8];
        short8 bl1 = *(const short8*)&hmA_lo[16 + col][ks * 32 + quad * 8];
        const int ko = ks * 16 * 512;
        #pragma unroll
        for (int mt = 0; mt < 4; ++mt) {
          short8 awh = *(const short8*)(w2h_b + ko + mt * 512);
          acc2[mt][0] = MFMA(awh, bh0, acc2[mt][0]);
          acc2[mt][0] = MFMA(awh, bl0, acc2[mt][0]);
          acc2[mt][1] = MFMA(awh, bh1, acc2[mt][1]);
          acc2[mt][1] = MFMA(awh, bl1, acc2[mt][1]);
        }
      }
      __syncthreads();
    }

    // ---- residual: h += acc2 + b2, packed b64 read/modify/write ----
    #pragma unroll
    for (int mt = 0; mt < 4; ++mt) {
      const int feat0 = (wave * 4 + mt) * 16 + quad * 4;
      float4 bb = *(const float4*)&b2l[feat0];
      #pragma unroll
      for (int nt = 0; nt < 2; ++nt) {
        const int row = nt * 16 + col;
        short4v oh = *(short4v*)&hA_hi[row][feat0];
        short4v ol = *(short4v*)&hA_lo[row][feat0];
        short4v nh, nl;
        #pragma unroll
        for (int p = 0; p < 4; ++p) {
          float hold = bf16_to_f(oh[p]) + bf16_to_f(ol[p]);
          float hnew = hold + acc2[mt][nt][p] + ((const float*)&bb)[p];
          short th, tl; splitf(hnew, th, tl);
          nh[p] = th; nl[p] = tl;
        }
        *(short4v*)&hA_hi[row][feat0] = nh;
        *(short4v*)&hA_lo[row][feat0] = nl;
      }
    }
    __syncthreads();
  }

  // ---- GEMM3': cw' = Wout^T @ h^T (+bout+cb+xhat), then distance ----
  floatx4 acc3[4][2];
  #pragma unroll
  for (int mt = 0; mt < 4; ++mt)
    #pragma unroll
    for (int nt = 0; nt < 2; ++nt) acc3[mt][nt] = zero4;

  const short* woh_b = wouth + (wave * 4) * 512 + lane8;
  #pragma unroll 2
  for (int ks = 0; ks < 8; ++ks) {
    short8 bh0 = *(const short8*)&hA_hi[col][ks * 32 + quad * 8];
    short8 bl0 = *(const short8*)&hA_lo[col][ks * 32 + quad * 8];
    short8 bh1 = *(const short8*)&hA_hi[16 + col][ks * 32 + quad * 8];
    short8 bl1 = *(const short8*)&hA_lo[16 + col][ks * 32 + quad * 8];
    const int ko = ks * 16 * 512;
    #pragma unroll
    for (int mt = 0; mt < 4; ++mt) {
      short8 awh = *(const short8*)(woh_b + ko + mt * 512);
      acc3[mt][0] = MFMA(awh, bh0, acc3[mt][0]);
      acc3[mt][0] = MFMA(awh, bl0, acc3[mt][0]);
      acc3[mt][1] = MFMA(awh, bh1, acc3[mt][1]);
      acc3[mt][1] = MFMA(awh, bl1, acc3[mt][1]);
    }
  }

  float s0 = 0.f, s1 = 0.f;
  const float* cbr0 = cb + (k0 + col) * D_;
  const float* cbr1 = cb + (k0 + 16 + col) * D_;
  #pragma unroll
  for (int mt = 0; mt < 4; ++mt) {
    const int d0 = (wave * 4 + mt) * 16 + quad * 4;
    float4 bo = *(const float4*)&bout[d0];
    float4 xv = *(const float4*)&x_s[d0];
    float4 xh = *(const float4*)&xh_s[d0];
    float4 c0 = *(const float4*)&cbr0[d0];
    float4 c1 = *(const float4*)&cbr1[d0];
    #pragma unroll
    for (int p = 0; p < 4; ++p) {
      float base = ((const float*)&bo)[p] + ((const float*)&xh)[p];
      float xx = ((const float*)&xv)[p];
      float cw0 = acc3[mt][0][p] + base + ((const float*)&c0)[p];
      s0 += cw0 * (cw0 - 2.f * xx);   // -||x||^2 const: argmin-invariant
      float cw1 = acc3[mt][1][p] + base + ((const float*)&c1)[p];
      s1 += cw1 * (cw1 - 2.f * xx);
    }
  }
  s0 += __shfl_xor(s0, 16, 64); s0 += __shfl_xor(s0, 32, 64);
  s1 += __shfl_xor(s1, 16, 64); s1 += __shfl_xor(s1, 32, 64);
  if (quad == 0) {
    dist_s[wave][col] = s0;
    dist_s[wave][16 + col] = s1;
  }
  __syncthreads();
  if (t < 32) {
    float d = dist_s[0][t] + dist_s[1][t] + dist_s[2][t] + dist_s[3][t];
    dists[b * (F_ * K_) + f * K_ + k0 + t] = d;
  }
}

// ---------------------------------------------------------------------------
// Top-8 candidates per b from approx dists (iterative selection).
__global__ void k_top8(const float* __restrict__ dists, int* __restrict__ topi) {
  __shared__ float ds[F_ * K_];
  __shared__ float bv[256];
  __shared__ int bi_s[256];
  const int b = blockIdx.x, t = threadIdx.x;
  for (int j = t; j < F_ * K_; j += 256) ds[j] = dists[b * (F_ * K_) + j];
  __syncthreads();
  for (int pass = 0; pass < 8; ++pass) {
    float best = 3.4e38f; int bi = 0;
    for (int j = t; j < F_ * K_; j += 256) {
      const float dv = ds[j];
      if (dv < best) { best = dv; bi = j; }
    }
    bv[t] = best; bi_s[t] = bi;
    __syncthreads();
    for (int s = 128; s > 0; s >>= 1) {
      if (t < s) {
        const float ov = bv[t + s]; const int oi = bi_s[t + s];
        if (ov < bv[t] || (ov == bv[t] && oi < bi_s[t])) { bv[t] = ov; bi_s[t] = oi; }
      }
      __syncthreads();
    }
    if (t == 0) { topi[b * 8 + pass] = bi_s[0]; ds[bi_s[0]] = 3.4e38f; }
    __syncthreads();
  }
}

// ---------------------------------------------------------------------------
// Exact fp32 rescore of one candidate row per block (same math as R2 pass).
__global__ void k_rescore(const float* __restrict__ u, const float* __restrict__ v,
                          const float* __restrict__ W1, const float* __restrict__ b1,
                          const float* __restrict__ W2, const float* __restrict__ b2,
                          const float* __restrict__ Wout, const float* __restrict__ bout,
                          const float* __restrict__ cb, const float* __restrict__ xhat,
                          const float* __restrict__ x, const int* __restrict__ topi,
                          float* __restrict__ resc) {
  __shared__ float hs[H_];
  __shared__ float hms[HFF_];
  __shared__ float red[256];
  const int bc = blockIdx.x, t = threadIdx.x;
  const int b = bc >> 3;
  const int idx = topi[bc];
  const int f = idx >> 8, k = idx & 255;
  const int bf = b * F_ + f;

  hs[t] = u[k * H_ + t] + v[bf * H_ + t];
  __syncthreads();
  for (int l = 0; l < 2; ++l) {
    const float* W1l = W1 + l * (H_ * HFF_);
    const float* W2l = W2 + l * (HFF_ * H_);
    float a0 = b1[l * HFF_ + t], a1 = b1[l * HFF_ + 256 + t];
    for (int i = 0; i < H_; ++i) {
      const float hv = hs[i];
      a0 = fmaf(hv, W1l[i * HFF_ + t], a0);
      a1 = fmaf(hv, W1l[i * HFF_ + 256 + t], a1);
    }
    hms[t] = fmaxf(a0, 0.f);
    hms[t + 256] = fmaxf(a1, 0.f);
    __syncthreads();
    float hn = hs[t] + b2[l * H_ + t];
    for (int jj = 0; jj < HFF_; ++jj)
      hn = fmaf(hms[jj], W2l[jj * H_ + t], hn);
    __syncthreads();
    hs[t] = hn;
    __syncthreads();
  }
  float cw = bout[t] + cb[k * D_ + t] + xhat[bf * D_ + t];
  for (int i = 0; i < H_; ++i) cw = fmaf(hs[i], Wout[i * D_ + t], cw);
  red[t] = cw * (cw - 2.f * x[b * D_ + t]);
  __syncthreads();
  for (int s = 128; s > 0; s >>= 1) {
    if (t < s) red[t] += red[t + s];
    __syncthreads();
  }
  if (t == 0) resc[bc] = red[0];
}

// ---------------------------------------------------------------------------
// Pick exact argmin among 8 rescored candidates; recompute winner; write out.
__global__ void k_final(const float* __restrict__ u, const float* __restrict__ v,
                        const float* __restrict__ W1, const float* __restrict__ b1,
                        const float* __restrict__ W2, const float* __restrict__ b2,
                        const float* __restrict__ Wout, const float* __restrict__ bout,
                        const float* __restrict__ cb, const float* __restrict__ xhat,
                        const int* __restrict__ codes, const int* __restrict__ topi,
                        const float* __restrict__ resc, float* __restrict__ out) {
  __shared__ float hs[H_];
  __shared__ float hms[HFF_];
  __shared__ int idx_sh;
  const int b = blockIdx.x, t = threadIdx.x;
  if (t == 0) {
    float bd = 3.4e38f; int bidx = 1 << 30;
    for (int c = 0; c < 8; ++c) {
      const float d = resc[b * 8 + c];
      const int ix = topi[b * 8 + c];
      if (d < bd || (d == bd && ix < bidx)) { bd = d; bidx = ix; }
    }
    idx_sh = bidx;
  }
  __syncthreads();
  const int idx = idx_sh;
  const int f = idx >> 8, k = idx & 255;
  const int bf = b * F_ + f;

  hs[t] = u[k * H_ + t] + v[bf * H_ + t];
  __syncthreads();
  for (int l = 0; l < 2; ++l) {
    const float* W1l = W1 + l * (H_ * HFF_);
    const float* W2l = W2 + l * (HFF_ * H_);
    float a0 = b1[l * HFF_ + t], a1 = b1[l * HFF_ + 256 + t];
    for (int i = 0; i < H_; ++i) {
      const float hv = hs[i];
      a0 = fmaf(hv, W1l[i * HFF_ + t], a0);
      a1 = fmaf(hv, W1l[i * HFF_ + 256 + t], a1);
    }
    hms[t] = fmaxf(a0, 0.f);
    hms[t + 256] = fmaxf(a1, 0.f);
    __syncthreads();
    float hn = hs[t] + b2[l * H_ + t];
    for (int jj = 0; jj < HFF_; ++jj)
      hn = fmaf(hms[jj], W2l[jj * H_ + t], hn);
    __syncthreads();
    hs[t] = hn;
    __syncthreads();
  }
  float cw = bout[t] + cb[k * D_ + t] + xhat[bf * D_ + t];
  for (int i = 0; i < H_; ++i) cw = fmaf(hs[i], Wout[i * D_ + t], cw);

  out[b * D_ + t] = cw;
  if (t < 2)
    out[B_ * D_ + t * B_ + b] = (float)codes[t * B_ + b];
  else if (t == 2)
    out[B_ * D_ + 2 * B_ + b] = (float)idx;
}

// ---------------------------------------------------------------------------
extern "C" void kernel_launch(void* const* d_in, const int* in_sizes, int n_in,
                              void* d_out, int out_size, void* d_ws, size_t ws_size,
                              hipStream_t stream) {
  const float* x    = (const float*)d_in[0];
  const float* xhat = (const float*)d_in[1];
  const int*   codes= (const int*)d_in[2];
  const float* cb   = (const float*)d_in[3];
  const float* Win  = (const float*)d_in[4];
  const float* bin  = (const float*)d_in[5];
  const float* Wcat = (const float*)d_in[6];
  const float* bcat = (const float*)d_in[7];
  const float* W1   = (const float*)d_in[8];
  const float* b1   = (const float*)d_in[9];
  const float* W2   = (const float*)d_in[10];
  const float* b2   = (const float*)d_in[11];
  const float* Wout = (const float*)d_in[12];
  const float* bout = (const float*)d_in[13];
  float* out = (float*)d_out;

  float* h0    = (float*)d_ws;                  // 65536 f
  float* u     = h0 + K_ * H_;                  // 65536 f
  float* v     = u + K_ * H_;                   // 262144 f
  float* dists = v + B_ * F_ * H_;              // 262144 f
  float* resc  = dists + B_ * F_ * K_;          // 1024 f
  int*   topi  = (int*)(resc + 1024);           // 1024 i
  int*   pad   = topi + 1024;                   // 128 pad (keeps 16B align)
  short* w1h   = (short*)(pad + 128);           // 262144 sh
  short* w1l   = w1h + 2 * H_ * HFF_;
  short* w2h   = w1l + 2 * H_ * HFF_;
  short* w2l   = w2h + 2 * HFF_ * H_;
  short* wouth = w2l + 2 * HFF_ * H_;
  short* woutl = wouth + H_ * D_;

  k_h0<<<K_, 256, 0, stream>>>(cb, Win, bin, h0);
  k_uv<<<K_ + B_ * F_, 256, 0, stream>>>(h0, Wcat, bcat, xhat, u, v);
  k_wfrag<<<512, 256, 0, stream>>>(W1, w1h, w1l, HFF_, 32);
  k_wfrag<<<512, 256, 0, stream>>>(W1 + H_ * HFF_, w1h + H_ * HFF_, w1l + H_ * HFF_, HFF_, 32);
  k_wfrag<<<512, 256, 0, stream>>>(W2, w2h, w2l, H_, 16);
  k_wfrag<<<512, 256, 0, stream>>>(W2 + HFF_ * H_, w2h + HFF_ * H_, w2l + HFF_ * H_, H_, 16);
  k_wfrag<<<256, 256, 0, stream>>>(Wout, wouth, woutl, D_, 16);

  k_main<<<B_ * F_ * (K_ / RT), 256, 0, stream>>>(u, v, w1h, w1l, b1, w2h, w2l, b2,
                                                  wouth, woutl, bout, cb, xhat, x, dists);
  k_top8<<<B_, 256, 0, stream>>>(dists, topi);
  k_rescore<<<B_ * 8, 256, 0, stream>>>(u, v, W1, b1, W2, b2, Wout, bout, cb, xhat,
                                        x, topi, resc);
  k_final<<<B_, 256, 0, stream>>>(u, v, W1, b1, W2, b2, Wout, bout, cb, xhat,
                                  codes, topi, resc, out);
}

// Round 7
// 627.649 us; speedup vs baseline: 1.7332x; 1.2855x over previous
//
#include <hip/hip_runtime.h>
#include <hip/hip_bf16.h>

// Shapes (fixed): B=128, F=8, K=256, D=256, H=256, HFF=512, L=2, M_PREV=2
#define B_   128
#define F_   8
#define K_   256
#define D_   256
#define H_   256
#define HFF_ 512
#define RT   64   // candidates per block (R7: was 32)

typedef _Float16 half8  __attribute__((ext_vector_type(8)));  // f16x8 MFMA frag
typedef _Float16 half4v __attribute__((ext_vector_type(4)));
typedef float floatx4   __attribute__((ext_vector_type(4)));  // MFMA acc

#define MFMAH(a,b,c) __builtin_amdgcn_mfma_f32_16x16x32_f16(a,b,c,0,0,0)

// ---------------------------------------------------------------------------
__global__ void k_h0(const float* __restrict__ cb, const float* __restrict__ Win,
                     const float* __restrict__ bin, float* __restrict__ h0) {
  __shared__ float row[D_];
  const int k = blockIdx.x, j = threadIdx.x;
  row[j] = cb[k * D_ + j];
  __syncthreads();
  float acc = bin[j];
  #pragma unroll 4
  for (int i = 0; i < D_; ++i) acc = fmaf(row[i], Win[i * H_ + j], acc);
  h0[k * H_ + j] = acc;
}

__global__ void k_uv(const float* __restrict__ h0, const float* __restrict__ Wcat,
                     const float* __restrict__ bcat, const float* __restrict__ xhat,
                     float* __restrict__ u, float* __restrict__ v) {
  __shared__ float row[D_];
  const int blk = blockIdx.x, j = threadIdx.x;
  if (blk < K_) {
    row[j] = h0[blk * H_ + j];
    __syncthreads();
    float acc = 0.f;
    #pragma unroll 4
    for (int i = 0; i < H_; ++i) acc = fmaf(row[i], Wcat[i * H_ + j], acc);
    u[blk * H_ + j] = acc;
  } else {
    const int bf = blk - K_;
    row[j] = xhat[bf * D_ + j];
    __syncthreads();
    float acc = bcat[j];
    #pragma unroll 4
    for (int i = 0; i < D_; ++i) acc = fmaf(row[i], Wcat[(H_ + i) * H_ + j], acc);
    v[bf * H_ + j] = acc;
  }
}

// ---------------------------------------------------------------------------
// Pre-shuffle a weight matrix [K x N] into MFMA fragment order, fp16 (RNE).
__global__ void k_wfrag16(const float* __restrict__ src, _Float16* __restrict__ dst,
                          int N, int NT) {
  const int e = blockIdx.x * 256 + threadIdx.x;
  const int jj = e & 7, lane = (e >> 3) & 63, r = e >> 9;
  const int ntile = r % NT, kstep = r / NT;
  const int row = kstep * 32 + (lane >> 4) * 8 + jj;
  const int colc = ntile * 16 + (lane & 15);
  dst[e] = (_Float16)src[row * N + colc];
}

// ---------------------------------------------------------------------------
// MFMA main kernel: C' = W^T @ h^T, fp16 single-term (rel err ~2^-12, 8x
// tighter than R6's 2-term bf16), 64 candidates/block. Weight frags stream
// from L2 as the A-operand; h/hm (fp16) live in LDS as the B-operand.
__global__ __launch_bounds__(256, 3) void k_main(
    const float* __restrict__ u, const float* __restrict__ v,
    const _Float16* __restrict__ w1f, const float* __restrict__ b1,
    const _Float16* __restrict__ w2f, const float* __restrict__ b2,
    const _Float16* __restrict__ woutf, const float* __restrict__ bout,
    const float* __restrict__ cb, const float* __restrict__ xhat,
    const float* __restrict__ x, float* __restrict__ dists) {
  __shared__ _Float16 hA[64][264];    // [candidate row][feature] 33792 B
  __shared__ _Float16 hmA[64][136];   // [row][chunk-local feature] 17408 B
  __shared__ float x_s[D_], xh_s[D_];
  __shared__ float dist_s[4][64];

  const int t = threadIdx.x;
  const int blk = blockIdx.x;
  const int bf = blk >> 2, k0 = (blk & 3) << 6;
  const int b = bf >> 3, f = bf & 7;
  const int wave = t >> 6, lane = t & 63;
  const int col = lane & 15, quad = lane >> 4;
  const int lane8 = lane * 8;

  x_s[t]  = x[b * D_ + t];
  xh_s[t] = xhat[bf * D_ + t];

  // stage h = u + v -> fp16, packed 16B writes. r=t>>2 (0..63), c0=(t&3)*64
  {
    const int r = t >> 2, c0 = (t & 3) * 64;
    const float* up = u + (k0 + r) * H_ + c0;
    const float* vp = v + bf * H_ + c0;
    #pragma unroll
    for (int j = 0; j < 64; j += 8) {
      float4 uA = *(const float4*)(up + j);
      float4 vA = *(const float4*)(vp + j);
      float4 uB = *(const float4*)(up + j + 4);
      float4 vB = *(const float4*)(vp + j + 4);
      half8 hv8;
      hv8[0] = (_Float16)(uA.x + vA.x); hv8[1] = (_Float16)(uA.y + vA.y);
      hv8[2] = (_Float16)(uA.z + vA.z); hv8[3] = (_Float16)(uA.w + vA.w);
      hv8[4] = (_Float16)(uB.x + vB.x); hv8[5] = (_Float16)(uB.y + vB.y);
      hv8[6] = (_Float16)(uB.z + vB.z); hv8[7] = (_Float16)(uB.w + vB.w);
      *(half8*)&hA[r][c0 + j] = hv8;
    }
  }
  __syncthreads();

  const floatx4 zero4 = {0.f, 0.f, 0.f, 0.f};

  #pragma unroll 1
  for (int l = 0; l < 2; ++l) {
    const _Float16* w1_l = w1f + l * (H_ * HFF_);
    const _Float16* w2_l = w2f + l * (HFF_ * H_);
    const float* b1l = b1 + l * HFF_;
    const float* b2l = b2 + l * H_;

    floatx4 acc2[4][4];   // [out-feature tile][candidate-row tile]
    #pragma unroll
    for (int mt = 0; mt < 4; ++mt)
      #pragma unroll
      for (int nt = 0; nt < 4; ++nt) acc2[mt][nt] = zero4;

    #pragma unroll 1
    for (int ch = 0; ch < 4; ++ch) {
      // ---- GEMM1': hm' = relu(W1[:,chunk]^T @ h^T + b1) ----
      floatx4 acc1[2][4];
      #pragma unroll
      for (int mt = 0; mt < 2; ++mt)
        #pragma unroll
        for (int nt = 0; nt < 4; ++nt) acc1[mt][nt] = zero4;

      const _Float16* w1_b = w1_l + (ch * 8 + wave * 2) * 512 + lane8;

      #pragma unroll 2
      for (int ks = 0; ks < 8; ++ks) {
        half8 b0 = *(const half8*)&hA[col][ks * 32 + quad * 8];
        half8 b1v = *(const half8*)&hA[16 + col][ks * 32 + quad * 8];
        half8 b2v = *(const half8*)&hA[32 + col][ks * 32 + quad * 8];
        half8 b3v = *(const half8*)&hA[48 + col][ks * 32 + quad * 8];
        const int ko = ks * 32 * 512;
        #pragma unroll
        for (int mt = 0; mt < 2; ++mt) {
          half8 aw = *(const half8*)(w1_b + ko + mt * 512);
          acc1[mt][0] = MFMAH(aw, b0, acc1[mt][0]);
          acc1[mt][1] = MFMAH(aw, b1v, acc1[mt][1]);
          acc1[mt][2] = MFMAH(aw, b2v, acc1[mt][2]);
          acc1[mt][3] = MFMAH(aw, b3v, acc1[mt][3]);
        }
      }
      // bias + relu -> fp16, packed 8B stores (4 consecutive features/lane)
      #pragma unroll
      for (int mt = 0; mt < 2; ++mt) {
        const int floc = (wave * 2 + mt) * 16 + quad * 4;
        float4 bb = *(const float4*)&b1l[ch * 128 + floc];
        #pragma unroll
        for (int nt = 0; nt < 4; ++nt) {
          const int row = nt * 16 + col;
          half4v nh;
          #pragma unroll
          for (int p = 0; p < 4; ++p)
            nh[p] = (_Float16)fmaxf(acc1[mt][nt][p] + ((const float*)&bb)[p], 0.f);
          *(half4v*)&hmA[row][floc] = nh;
        }
      }
      __syncthreads();

      // ---- GEMM2': acc2 += W2[chunk,:]^T @ hm'^T ----
      const _Float16* w2_b = w2_l + (ch * 64 + wave * 4) * 512 + lane8;
      #pragma unroll 2
      for (int ks = 0; ks < 4; ++ks) {
        half8 b0 = *(const half8*)&hmA[col][ks * 32 + quad * 8];
        half8 b1v = *(const half8*)&hmA[16 + col][ks * 32 + quad * 8];
        half8 b2v = *(const half8*)&hmA[32 + col][ks * 32 + quad * 8];
        half8 b3v = *(const half8*)&hmA[48 + col][ks * 32 + quad * 8];
        const int ko = ks * 16 * 512;
        #pragma unroll
        for (int mt = 0; mt < 4; ++mt) {
          half8 aw = *(const half8*)(w2_b + ko + mt * 512);
          acc2[mt][0] = MFMAH(aw, b0, acc2[mt][0]);
          acc2[mt][1] = MFMAH(aw, b1v, acc2[mt][1]);
          acc2[mt][2] = MFMAH(aw, b2v, acc2[mt][2]);
          acc2[mt][3] = MFMAH(aw, b3v, acc2[mt][3]);
        }
      }
      __syncthreads();
    }

    // ---- residual: h += acc2 + b2, packed 8B read/modify/write ----
    #pragma unroll
    for (int mt = 0; mt < 4; ++mt) {
      const int feat0 = (wave * 4 + mt) * 16 + quad * 4;
      float4 bb = *(const float4*)&b2l[feat0];
      #pragma unroll
      for (int nt = 0; nt < 4; ++nt) {
        const int row = nt * 16 + col;
        half4v oh = *(half4v*)&hA[row][feat0];
        half4v nh;
        #pragma unroll
        for (int p = 0; p < 4; ++p)
          nh[p] = (_Float16)((float)oh[p] + acc2[mt][nt][p] + ((const float*)&bb)[p]);
        *(half4v*)&hA[row][feat0] = nh;
      }
    }
    __syncthreads();
  }

  // ---- GEMM3': cw' = Wout^T @ h^T (+bout+cb+xhat), then distance ----
  floatx4 acc3[4][4];
  #pragma unroll
  for (int mt = 0; mt < 4; ++mt)
    #pragma unroll
    for (int nt = 0; nt < 4; ++nt) acc3[mt][nt] = zero4;

  const _Float16* wo_b = woutf + (wave * 4) * 512 + lane8;
  #pragma unroll 2
  for (int ks = 0; ks < 8; ++ks) {
    half8 b0 = *(const half8*)&hA[col][ks * 32 + quad * 8];
    half8 b1v = *(const half8*)&hA[16 + col][ks * 32 + quad * 8];
    half8 b2v = *(const half8*)&hA[32 + col][ks * 32 + quad * 8];
    half8 b3v = *(const half8*)&hA[48 + col][ks * 32 + quad * 8];
    const int ko = ks * 16 * 512;
    #pragma unroll
    for (int mt = 0; mt < 4; ++mt) {
      half8 aw = *(const half8*)(wo_b + ko + mt * 512);
      acc3[mt][0] = MFMAH(aw, b0, acc3[mt][0]);
      acc3[mt][1] = MFMAH(aw, b1v, acc3[mt][1]);
      acc3[mt][2] = MFMAH(aw, b2v, acc3[mt][2]);
      acc3[mt][3] = MFMAH(aw, b3v, acc3[mt][3]);
    }
  }

  float s[4] = {0.f, 0.f, 0.f, 0.f};
  #pragma unroll
  for (int mt = 0; mt < 4; ++mt) {
    const int d0 = (wave * 4 + mt) * 16 + quad * 4;
    float4 bo = *(const float4*)&bout[d0];
    float4 xv = *(const float4*)&x_s[d0];
    float4 xh4 = *(const float4*)&xh_s[d0];
    #pragma unroll
    for (int nt = 0; nt < 4; ++nt) {
      float4 cbv = *(const float4*)&cb[(k0 + nt * 16 + col) * D_ + d0];
      #pragma unroll
      for (int p = 0; p < 4; ++p) {
        float base = ((const float*)&bo)[p] + ((const float*)&xh4)[p];
        float xx = ((const float*)&xv)[p];
        float cw = acc3[mt][nt][p] + base + ((const float*)&cbv)[p];
        s[nt] += cw * (cw - 2.f * xx);   // -||x||^2 const: argmin-invariant
      }
    }
  }
  #pragma unroll
  for (int nt = 0; nt < 4; ++nt) {
    s[nt] += __shfl_xor(s[nt], 16, 64);
    s[nt] += __shfl_xor(s[nt], 32, 64);
  }
  if (quad == 0) {
    #pragma unroll
    for (int nt = 0; nt < 4; ++nt)
      dist_s[wave][nt * 16 + col] = s[nt];
  }
  __syncthreads();
  if (t < 64) {
    float d = dist_s[0][t] + dist_s[1][t] + dist_s[2][t] + dist_s[3][t];
    dists[b * (F_ * K_) + f * K_ + k0 + t] = d;
  }
}

// ---------------------------------------------------------------------------
// Top-8 candidates per b from approx dists (iterative selection).
__global__ void k_top8(const float* __restrict__ dists, int* __restrict__ topi) {
  __shared__ float ds[F_ * K_];
  __shared__ float bv[256];
  __shared__ int bi_s[256];
  const int b = blockIdx.x, t = threadIdx.x;
  for (int j = t; j < F_ * K_; j += 256) ds[j] = dists[b * (F_ * K_) + j];
  __syncthreads();
  for (int pass = 0; pass < 8; ++pass) {
    float best = 3.4e38f; int bi = 0;
    for (int j = t; j < F_ * K_; j += 256) {
      const float dv = ds[j];
      if (dv < best) { best = dv; bi = j; }
    }
    bv[t] = best; bi_s[t] = bi;
    __syncthreads();
    for (int s = 128; s > 0; s >>= 1) {
      if (t < s) {
        const float ov = bv[t + s]; const int oi = bi_s[t + s];
        if (ov < bv[t] || (ov == bv[t] && oi < bi_s[t])) { bv[t] = ov; bi_s[t] = oi; }
      }
      __syncthreads();
    }
    if (t == 0) { topi[b * 8 + pass] = bi_s[0]; ds[bi_s[0]] = 3.4e38f; }
    __syncthreads();
  }
}

// ---------------------------------------------------------------------------
// Exact fp32 rescore of one candidate row per block (same math as R2 pass).
__global__ void k_rescore(const float* __restrict__ u, const float* __restrict__ v,
                          const float* __restrict__ W1, const float* __restrict__ b1,
                          const float* __restrict__ W2, const float* __restrict__ b2,
                          const float* __restrict__ Wout, const float* __restrict__ bout,
                          const float* __restrict__ cb, const float* __restrict__ xhat,
                          const float* __restrict__ x, const int* __restrict__ topi,
                          float* __restrict__ resc) {
  __shared__ float hs[H_];
  __shared__ float hms[HFF_];
  __shared__ float red[256];
  const int bc = blockIdx.x, t = threadIdx.x;
  const int b = bc >> 3;
  const int idx = topi[bc];
  const int f = idx >> 8, k = idx & 255;
  const int bf = b * F_ + f;

  hs[t] = u[k * H_ + t] + v[bf * H_ + t];
  __syncthreads();
  for (int l = 0; l < 2; ++l) {
    const float* W1l = W1 + l * (H_ * HFF_);
    const float* W2l = W2 + l * (HFF_ * H_);
    float a0 = b1[l * HFF_ + t], a1 = b1[l * HFF_ + 256 + t];
    for (int i = 0; i < H_; ++i) {
      const float hv = hs[i];
      a0 = fmaf(hv, W1l[i * HFF_ + t], a0);
      a1 = fmaf(hv, W1l[i * HFF_ + 256 + t], a1);
    }
    hms[t] = fmaxf(a0, 0.f);
    hms[t + 256] = fmaxf(a1, 0.f);
    __syncthreads();
    float hn = hs[t] + b2[l * H_ + t];
    for (int jj = 0; jj < HFF_; ++jj)
      hn = fmaf(hms[jj], W2l[jj * H_ + t], hn);
    __syncthreads();
    hs[t] = hn;
    __syncthreads();
  }
  float cw = bout[t] + cb[k * D_ + t] + xhat[bf * D_ + t];
  for (int i = 0; i < H_; ++i) cw = fmaf(hs[i], Wout[i * D_ + t], cw);
  red[t] = cw * (cw - 2.f * x[b * D_ + t]);
  __syncthreads();
  for (int s = 128; s > 0; s >>= 1) {
    if (t < s) red[t] += red[t + s];
    __syncthreads();
  }
  if (t == 0) resc[bc] = red[0];
}

// ---------------------------------------------------------------------------
// Pick exact argmin among 8 rescored candidates; recompute winner; write out.
__global__ void k_final(const float* __restrict__ u, const float* __restrict__ v,
                        const float* __restrict__ W1, const float* __restrict__ b1,
                        const float* __restrict__ W2, const float* __restrict__ b2,
                        const float* __restrict__ Wout, const float* __restrict__ bout,
                        const float* __restrict__ cb, const float* __restrict__ xhat,
                        const int* __restrict__ codes, const int* __restrict__ topi,
                        const float* __restrict__ resc, float* __restrict__ out) {
  __shared__ float hs[H_];
  __shared__ float hms[HFF_];
  __shared__ int idx_sh;
  const int b = blockIdx.x, t = threadIdx.x;
  if (t == 0) {
    float bd = 3.4e38f; int bidx = 1 << 30;
    for (int c = 0; c < 8; ++c) {
      const float d = resc[b * 8 + c];
      const int ix = topi[b * 8 + c];
      if (d < bd || (d == bd && ix < bidx)) { bd = d; bidx = ix; }
    }
    idx_sh = bidx;
  }
  __syncthreads();
  const int idx = idx_sh;
  const int f = idx >> 8, k = idx & 255;
  const int bf = b * F_ + f;

  hs[t] = u[k * H_ + t] + v[bf * H_ + t];
  __syncthreads();
  for (int l = 0; l < 2; ++l) {
    const float* W1l = W1 + l * (H_ * HFF_);
    const float* W2l = W2 + l * (HFF_ * H_);
    float a0 = b1[l * HFF_ + t], a1 = b1[l * HFF_ + 256 + t];
    for (int i = 0; i < H_; ++i) {
      const float hv = hs[i];
      a0 = fmaf(hv, W1l[i * HFF_ + t], a0);
      a1 = fmaf(hv, W1l[i * HFF_ + 256 + t], a1);
    }
    hms[t] = fmaxf(a0, 0.f);
    hms[t + 256] = fmaxf(a1, 0.f);
    __syncthreads();
    float hn = hs[t] + b2[l * H_ + t];
    for (int jj = 0; jj < HFF_; ++jj)
      hn = fmaf(hms[jj], W2l[jj * H_ + t], hn);
    __syncthreads();
    hs[t] = hn;
    __syncthreads();
  }
  float cw = bout[t] + cb[k * D_ + t] + xhat[bf * D_ + t];
  for (int i = 0; i < H_; ++i) cw = fmaf(hs[i], Wout[i * D_ + t], cw);

  out[b * D_ + t] = cw;
  if (t < 2)
    out[B_ * D_ + t * B_ + b] = (float)codes[t * B_ + b];
  else if (t == 2)
    out[B_ * D_ + 2 * B_ + b] = (float)idx;
}

// ---------------------------------------------------------------------------
extern "C" void kernel_launch(void* const* d_in, const int* in_sizes, int n_in,
                              void* d_out, int out_size, void* d_ws, size_t ws_size,
                              hipStream_t stream) {
  const float* x    = (const float*)d_in[0];
  const float* xhat = (const float*)d_in[1];
  const int*   codes= (const int*)d_in[2];
  const float* cb   = (const float*)d_in[3];
  const float* Win  = (const float*)d_in[4];
  const float* bin  = (const float*)d_in[5];
  const float* Wcat = (const float*)d_in[6];
  const float* bcat = (const float*)d_in[7];
  const float* W1   = (const float*)d_in[8];
  const float* b1   = (const float*)d_in[9];
  const float* W2   = (const float*)d_in[10];
  const float* b2   = (const float*)d_in[11];
  const float* Wout = (const float*)d_in[12];
  const float* bout = (const float*)d_in[13];
  float* out = (float*)d_out;

  float* h0    = (float*)d_ws;                  // 65536 f
  float* u     = h0 + K_ * H_;                  // 65536 f
  float* v     = u + K_ * H_;                   // 262144 f
  float* dists = v + B_ * F_ * H_;              // 262144 f
  float* resc  = dists + B_ * F_ * K_;          // 1024 f
  int*   topi  = (int*)(resc + 1024);           // 1024 i
  int*   pad   = topi + 1024;                   // 128 pad (keeps 16B align)
  _Float16* w1f  = (_Float16*)(pad + 128);      // 2*H*HFF halves
  _Float16* w2f  = w1f + 2 * H_ * HFF_;
  _Float16* wof  = w2f + 2 * HFF_ * H_;

  k_h0<<<K_, 256, 0, stream>>>(cb, Win, bin, h0);
  k_uv<<<K_ + B_ * F_, 256, 0, stream>>>(h0, Wcat, bcat, xhat, u, v);
  k_wfrag16<<<512, 256, 0, stream>>>(W1, w1f, HFF_, 32);
  k_wfrag16<<<512, 256, 0, stream>>>(W1 + H_ * HFF_, w1f + H_ * HFF_, HFF_, 32);
  k_wfrag16<<<512, 256, 0, stream>>>(W2, w2f, H_, 16);
  k_wfrag16<<<512, 256, 0, stream>>>(W2 + HFF_ * H_, w2f + HFF_ * H_, H_, 16);
  k_wfrag16<<<256, 256, 0, stream>>>(Wout, wof, D_, 16);

  k_main<<<B_ * F_ * (K_ / RT), 256, 0, stream>>>(u, v, w1f, b1, w2f, b2,
                                                  wof, bout, cb, xhat, x, dists);
  k_top8<<<B_, 256, 0, stream>>>(dists, topi);
  k_rescore<<<B_ * 8, 256, 0, stream>>>(u, v, W1, b1, W2, b2, Wout, bout, cb, xhat,
                                        x, topi, resc);
  k_final<<<B_, 256, 0, stream>>>(u, v, W1, b1, W2, b2, Wout, bout, cb, xhat,
                                  codes, topi, resc, out);
}

// Round 8
// 568.244 us; speedup vs baseline: 1.9144x; 1.1045x over previous
//
#include <hip/hip_runtime.h>
#include <hip/hip_bf16.h>

// Shapes (fixed): B=128, F=8, K=256, D=256, H=256, HFF=512, L=2, M_PREV=2
#define B_   128
#define F_   8
#define K_   256
#define D_   256
#define H_   256
#define HFF_ 512
#define RT   64   // candidates per block

typedef _Float16 half8  __attribute__((ext_vector_type(8)));  // f16x8 MFMA frag
typedef _Float16 half4v __attribute__((ext_vector_type(4)));
typedef float floatx4   __attribute__((ext_vector_type(4)));  // MFMA acc

#define MFMAH(a,b,c) __builtin_amdgcn_mfma_f32_16x16x32_f16(a,b,c,0,0,0)

// LDS strides (halves): 260 -> 130 dwords == 2 mod 32 (conflict-free b128);
// 132 -> 66 dwords == 2 mod 32. Total LDS 53248 B -> 3 blocks/CU (R8).
#define HA_S  260
#define HMA_S 132

// ---------------------------------------------------------------------------
__global__ void k_h0(const float* __restrict__ cb, const float* __restrict__ Win,
                     const float* __restrict__ bin, float* __restrict__ h0) {
  __shared__ float row[D_];
  const int k = blockIdx.x, j = threadIdx.x;
  row[j] = cb[k * D_ + j];
  __syncthreads();
  float acc = bin[j];
  #pragma unroll 4
  for (int i = 0; i < D_; ++i) acc = fmaf(row[i], Win[i * H_ + j], acc);
  h0[k * H_ + j] = acc;
}

__global__ void k_uv(const float* __restrict__ h0, const float* __restrict__ Wcat,
                     const float* __restrict__ bcat, const float* __restrict__ xhat,
                     float* __restrict__ u, float* __restrict__ v) {
  __shared__ float row[D_];
  const int blk = blockIdx.x, j = threadIdx.x;
  if (blk < K_) {
    row[j] = h0[blk * H_ + j];
    __syncthreads();
    float acc = 0.f;
    #pragma unroll 4
    for (int i = 0; i < H_; ++i) acc = fmaf(row[i], Wcat[i * H_ + j], acc);
    u[blk * H_ + j] = acc;
  } else {
    const int bf = blk - K_;
    row[j] = xhat[bf * D_ + j];
    __syncthreads();
    float acc = bcat[j];
    #pragma unroll 4
    for (int i = 0; i < D_; ++i) acc = fmaf(row[i], Wcat[(H_ + i) * H_ + j], acc);
    v[bf * H_ + j] = acc;
  }
}

// ---------------------------------------------------------------------------
// One-shot weight fragment shuffle (R8: merged 5 launches into 1).
// Element ranges: [0,262144) W1 (2 layers), [262144,524288) W2, rest Wout.
__global__ void k_wfrag16_all(const float* __restrict__ W1,
                              const float* __restrict__ W2,
                              const float* __restrict__ Wout,
                              _Float16* __restrict__ w1f,
                              _Float16* __restrict__ w2f,
                              _Float16* __restrict__ wof) {
  const int e = blockIdx.x * 256 + threadIdx.x;
  const float* src; _Float16* dst; int N, NT, le;
  if (e < 262144) {
    const int layer = e >> 17; le = e & 131071;
    src = W1 + layer * (H_ * HFF_); dst = w1f + layer * (H_ * HFF_);
    N = HFF_; NT = 32;
  } else if (e < 524288) {
    const int e2 = e - 262144;
    const int layer = e2 >> 17; le = e2 & 131071;
    src = W2 + layer * (HFF_ * H_); dst = w2f + layer * (HFF_ * H_);
    N = H_; NT = 16;
  } else {
    le = e - 524288; src = Wout; dst = wof; N = D_; NT = 16;
  }
  const int jj = le & 7, lane = (le >> 3) & 63, r = le >> 9;
  const int ntile = r % NT, kstep = r / NT;
  const int row = kstep * 32 + (lane >> 4) * 8 + jj;
  const int colc = ntile * 16 + (lane & 15);
  dst[le] = (_Float16)src[row * N + colc];
}

// ---------------------------------------------------------------------------
// MFMA main kernel: C' = W^T @ h^T, fp16 single-term, 64 candidates/block.
__global__ __launch_bounds__(256, 3) void k_main(
    const float* __restrict__ u, const float* __restrict__ v,
    const _Float16* __restrict__ w1f, const float* __restrict__ b1,
    const _Float16* __restrict__ w2f, const float* __restrict__ b2,
    const _Float16* __restrict__ woutf, const float* __restrict__ bout,
    const float* __restrict__ cb, const float* __restrict__ xhat,
    const float* __restrict__ x, float* __restrict__ dists) {
  __shared__ _Float16 hA[64][HA_S];    // 33280 B
  __shared__ _Float16 hmA[64][HMA_S];  // 16896 B
  __shared__ float x_s[D_], xh_s[D_];  // 2048 B
  __shared__ float dist_s[4][64];      // 1024 B

  const int t = threadIdx.x;
  const int blk = blockIdx.x;
  const int bf = blk >> 2, k0 = (blk & 3) << 6;
  const int b = bf >> 3, f = bf & 7;
  const int wave = t >> 6, lane = t & 63;
  const int col = lane & 15, quad = lane >> 4;
  const int lane8 = lane * 8;

  x_s[t]  = x[b * D_ + t];
  xh_s[t] = xhat[bf * D_ + t];

  // stage h = u + v -> fp16, packed 16B writes
  {
    const int r = t >> 2, c0 = (t & 3) * 64;
    const float* up = u + (k0 + r) * H_ + c0;
    const float* vp = v + bf * H_ + c0;
    #pragma unroll
    for (int j = 0; j < 64; j += 8) {
      float4 uA = *(const float4*)(up + j);
      float4 vA = *(const float4*)(vp + j);
      float4 uB = *(const float4*)(up + j + 4);
      float4 vB = *(const float4*)(vp + j + 4);
      half8 hv8;
      hv8[0] = (_Float16)(uA.x + vA.x); hv8[1] = (_Float16)(uA.y + vA.y);
      hv8[2] = (_Float16)(uA.z + vA.z); hv8[3] = (_Float16)(uA.w + vA.w);
      hv8[4] = (_Float16)(uB.x + vB.x); hv8[5] = (_Float16)(uB.y + vB.y);
      hv8[6] = (_Float16)(uB.z + vB.z); hv8[7] = (_Float16)(uB.w + vB.w);
      *(half8*)&hA[r][c0 + j] = hv8;
    }
  }
  __syncthreads();

  const floatx4 zero4 = {0.f, 0.f, 0.f, 0.f};

  #pragma unroll 1
  for (int l = 0; l < 2; ++l) {
    const _Float16* w1_l = w1f + l * (H_ * HFF_);
    const _Float16* w2_l = w2f + l * (HFF_ * H_);
    const float* b1l = b1 + l * HFF_;
    const float* b2l = b2 + l * H_;

    floatx4 acc2[4][4];   // [out-feature tile][candidate-row tile]
    #pragma unroll
    for (int mt = 0; mt < 4; ++mt)
      #pragma unroll
      for (int nt = 0; nt < 4; ++nt) acc2[mt][nt] = zero4;

    #pragma unroll 1
    for (int ch = 0; ch < 4; ++ch) {
      // ---- GEMM1': hm' = relu(W1[:,chunk]^T @ h^T + b1) ----
      floatx4 acc1[2][4];
      #pragma unroll
      for (int mt = 0; mt < 2; ++mt)
        #pragma unroll
        for (int nt = 0; nt < 4; ++nt) acc1[mt][nt] = zero4;

      const _Float16* w1_b = w1_l + (ch * 8 + wave * 2) * 512 + lane8;

      #pragma unroll 2
      for (int ks = 0; ks < 8; ++ks) {
        half8 b0 = *(const half8*)&hA[col][ks * 32 + quad * 8];
        half8 b1v = *(const half8*)&hA[16 + col][ks * 32 + quad * 8];
        half8 b2v = *(const half8*)&hA[32 + col][ks * 32 + quad * 8];
        half8 b3v = *(const half8*)&hA[48 + col][ks * 32 + quad * 8];
        const int ko = ks * 32 * 512;
        #pragma unroll
        for (int mt = 0; mt < 2; ++mt) {
          half8 aw = *(const half8*)(w1_b + ko + mt * 512);
          acc1[mt][0] = MFMAH(aw, b0, acc1[mt][0]);
          acc1[mt][1] = MFMAH(aw, b1v, acc1[mt][1]);
          acc1[mt][2] = MFMAH(aw, b2v, acc1[mt][2]);
          acc1[mt][3] = MFMAH(aw, b3v, acc1[mt][3]);
        }
      }
      // bias + relu -> fp16, packed 8B stores (4 consecutive features/lane)
      #pragma unroll
      for (int mt = 0; mt < 2; ++mt) {
        const int floc = (wave * 2 + mt) * 16 + quad * 4;
        float4 bb = *(const float4*)&b1l[ch * 128 + floc];
        #pragma unroll
        for (int nt = 0; nt < 4; ++nt) {
          const int row = nt * 16 + col;
          half4v nh;
          #pragma unroll
          for (int p = 0; p < 4; ++p)
            nh[p] = (_Float16)fmaxf(acc1[mt][nt][p] + ((const float*)&bb)[p], 0.f);
          *(half4v*)&hmA[row][floc] = nh;
        }
      }
      __syncthreads();

      // ---- GEMM2': acc2 += W2[chunk,:]^T @ hm'^T ----
      const _Float16* w2_b = w2_l + (ch * 64 + wave * 4) * 512 + lane8;
      #pragma unroll 2
      for (int ks = 0; ks < 4; ++ks) {
        half8 b0 = *(const half8*)&hmA[col][ks * 32 + quad * 8];
        half8 b1v = *(const half8*)&hmA[16 + col][ks * 32 + quad * 8];
        half8 b2v = *(const half8*)&hmA[32 + col][ks * 32 + quad * 8];
        half8 b3v = *(const half8*)&hmA[48 + col][ks * 32 + quad * 8];
        const int ko = ks * 16 * 512;
        #pragma unroll
        for (int mt = 0; mt < 4; ++mt) {
          half8 aw = *(const half8*)(w2_b + ko + mt * 512);
          acc2[mt][0] = MFMAH(aw, b0, acc2[mt][0]);
          acc2[mt][1] = MFMAH(aw, b1v, acc2[mt][1]);
          acc2[mt][2] = MFMAH(aw, b2v, acc2[mt][2]);
          acc2[mt][3] = MFMAH(aw, b3v, acc2[mt][3]);
        }
      }
      __syncthreads();
    }

    // ---- residual: h += acc2 + b2, packed 8B read/modify/write ----
    #pragma unroll
    for (int mt = 0; mt < 4; ++mt) {
      const int feat0 = (wave * 4 + mt) * 16 + quad * 4;
      float4 bb = *(const float4*)&b2l[feat0];
      #pragma unroll
      for (int nt = 0; nt < 4; ++nt) {
        const int row = nt * 16 + col;
        half4v oh = *(half4v*)&hA[row][feat0];
        half4v nh;
        #pragma unroll
        for (int p = 0; p < 4; ++p)
          nh[p] = (_Float16)((float)oh[p] + acc2[mt][nt][p] + ((const float*)&bb)[p]);
        *(half4v*)&hA[row][feat0] = nh;
      }
    }
    __syncthreads();
  }

  // ---- GEMM3': cw' = Wout^T @ h^T (+bout+cb+xhat), then distance ----
  floatx4 acc3[4][4];
  #pragma unroll
  for (int mt = 0; mt < 4; ++mt)
    #pragma unroll
    for (int nt = 0; nt < 4; ++nt) acc3[mt][nt] = zero4;

  const _Float16* wo_b = woutf + (wave * 4) * 512 + lane8;
  #pragma unroll 2
  for (int ks = 0; ks < 8; ++ks) {
    half8 b0 = *(const half8*)&hA[col][ks * 32 + quad * 8];
    half8 b1v = *(const half8*)&hA[16 + col][ks * 32 + quad * 8];
    half8 b2v = *(const half8*)&hA[32 + col][ks * 32 + quad * 8];
    half8 b3v = *(const half8*)&hA[48 + col][ks * 32 + quad * 8];
    const int ko = ks * 16 * 512;
    #pragma unroll
    for (int mt = 0; mt < 4; ++mt) {
      half8 aw = *(const half8*)(wo_b + ko + mt * 512);
      acc3[mt][0] = MFMAH(aw, b0, acc3[mt][0]);
      acc3[mt][1] = MFMAH(aw, b1v, acc3[mt][1]);
      acc3[mt][2] = MFMAH(aw, b2v, acc3[mt][2]);
      acc3[mt][3] = MFMAH(aw, b3v, acc3[mt][3]);
    }
  }

  float s[4] = {0.f, 0.f, 0.f, 0.f};
  #pragma unroll
  for (int mt = 0; mt < 4; ++mt) {
    const int d0 = (wave * 4 + mt) * 16 + quad * 4;
    float4 bo = *(const float4*)&bout[d0];
    float4 xv = *(const float4*)&x_s[d0];
    float4 xh4 = *(const float4*)&xh_s[d0];
    #pragma unroll
    for (int nt = 0; nt < 4; ++nt) {
      float4 cbv = *(const float4*)&cb[(k0 + nt * 16 + col) * D_ + d0];
      #pragma unroll
      for (int p = 0; p < 4; ++p) {
        float base = ((const float*)&bo)[p] + ((const float*)&xh4)[p];
        float xx = ((const float*)&xv)[p];
        float cw = acc3[mt][nt][p] + base + ((const float*)&cbv)[p];
        s[nt] += cw * (cw - 2.f * xx);   // -||x||^2 const: argmin-invariant
      }
    }
  }
  #pragma unroll
  for (int nt = 0; nt < 4; ++nt) {
    s[nt] += __shfl_xor(s[nt], 16, 64);
    s[nt] += __shfl_xor(s[nt], 32, 64);
  }
  if (quad == 0) {
    #pragma unroll
    for (int nt = 0; nt < 4; ++nt)
      dist_s[wave][nt * 16 + col] = s[nt];
  }
  __syncthreads();
  if (t < 64) {
    float d = dist_s[0][t] + dist_s[1][t] + dist_s[2][t] + dist_s[3][t];
    dists[b * (F_ * K_) + f * K_ + k0 + t] = d;
  }
}

// ---------------------------------------------------------------------------
// Top-8 candidates per b from approx dists (iterative selection).
__global__ void k_top8(const float* __restrict__ dists, int* __restrict__ topi) {
  __shared__ float ds[F_ * K_];
  __shared__ float bv[256];
  __shared__ int bi_s[256];
  const int b = blockIdx.x, t = threadIdx.x;
  for (int j = t; j < F_ * K_; j += 256) ds[j] = dists[b * (F_ * K_) + j];
  __syncthreads();
  for (int pass = 0; pass < 8; ++pass) {
    float best = 3.4e38f; int bi = 0;
    for (int j = t; j < F_ * K_; j += 256) {
      const float dv = ds[j];
      if (dv < best) { best = dv; bi = j; }
    }
    bv[t] = best; bi_s[t] = bi;
    __syncthreads();
    for (int s = 128; s > 0; s >>= 1) {
      if (t < s) {
        const float ov = bv[t + s]; const int oi = bi_s[t + s];
        if (ov < bv[t] || (ov == bv[t] && oi < bi_s[t])) { bv[t] = ov; bi_s[t] = oi; }
      }
      __syncthreads();
    }
    if (t == 0) { topi[b * 8 + pass] = bi_s[0]; ds[bi_s[0]] = 3.4e38f; }
    __syncthreads();
  }
}

// ---------------------------------------------------------------------------
// Exact fp32 rescore of one candidate row per block (same math as R2 pass).
__global__ void k_rescore(const float* __restrict__ u, const float* __restrict__ v,
                          const float* __restrict__ W1, const float* __restrict__ b1,
                          const float* __restrict__ W2, const float* __restrict__ b2,
                          const float* __restrict__ Wout, const float* __restrict__ bout,
                          const float* __restrict__ cb, const float* __restrict__ xhat,
                          const float* __restrict__ x, const int* __restrict__ topi,
                          float* __restrict__ resc) {
  __shared__ float hs[H_];
  __shared__ float hms[HFF_];
  __shared__ float red[256];
  const int bc = blockIdx.x, t = threadIdx.x;
  const int b = bc >> 3;
  const int idx = topi[bc];
  const int f = idx >> 8, k = idx & 255;
  const int bf = b * F_ + f;

  hs[t] = u[k * H_ + t] + v[bf * H_ + t];
  __syncthreads();
  for (int l = 0; l < 2; ++l) {
    const float* W1l = W1 + l * (H_ * HFF_);
    const float* W2l = W2 + l * (HFF_ * H_);
    float a0 = b1[l * HFF_ + t], a1 = b1[l * HFF_ + 256 + t];
    for (int i = 0; i < H_; ++i) {
      const float hv = hs[i];
      a0 = fmaf(hv, W1l[i * HFF_ + t], a0);
      a1 = fmaf(hv, W1l[i * HFF_ + 256 + t], a1);
    }
    hms[t] = fmaxf(a0, 0.f);
    hms[t + 256] = fmaxf(a1, 0.f);
    __syncthreads();
    float hn = hs[t] + b2[l * H_ + t];
    for (int jj = 0; jj < HFF_; ++jj)
      hn = fmaf(hms[jj], W2l[jj * H_ + t], hn);
    __syncthreads();
    hs[t] = hn;
    __syncthreads();
  }
  float cw = bout[t] + cb[k * D_ + t] + xhat[bf * D_ + t];
  for (int i = 0; i < H_; ++i) cw = fmaf(hs[i], Wout[i * D_ + t], cw);
  red[t] = cw * (cw - 2.f * x[b * D_ + t]);
  __syncthreads();
  for (int s = 128; s > 0; s >>= 1) {
    if (t < s) red[t] += red[t + s];
    __syncthreads();
  }
  if (t == 0) resc[bc] = red[0];
}

// ---------------------------------------------------------------------------
// Pick exact argmin among 8 rescored candidates; recompute winner; write out.
__global__ void k_final(const float* __restrict__ u, const float* __restrict__ v,
                        const float* __restrict__ W1, const float* __restrict__ b1,
                        const float* __restrict__ W2, const float* __restrict__ b2,
                        const float* __restrict__ Wout, const float* __restrict__ bout,
                        const float* __restrict__ cb, const float* __restrict__ xhat,
                        const int* __restrict__ codes, const int* __restrict__ topi,
                        const float* __restrict__ resc, float* __restrict__ out) {
  __shared__ float hs[H_];
  __shared__ float hms[HFF_];
  __shared__ int idx_sh;
  const int b = blockIdx.x, t = threadIdx.x;
  if (t == 0) {
    float bd = 3.4e38f; int bidx = 1 << 30;
    for (int c = 0; c < 8; ++c) {
      const float d = resc[b * 8 + c];
      const int ix = topi[b * 8 + c];
      if (d < bd || (d == bd && ix < bidx)) { bd = d; bidx = ix; }
    }
    idx_sh = bidx;
  }
  __syncthreads();
  const int idx = idx_sh;
  const int f = idx >> 8, k = idx & 255;
  const int bf = b * F_ + f;

  hs[t] = u[k * H_ + t] + v[bf * H_ + t];
  __syncthreads();
  for (int l = 0; l < 2; ++l) {
    const float* W1l = W1 + l * (H_ * HFF_);
    const float* W2l = W2 + l * (HFF_ * H_);
    float a0 = b1[l * HFF_ + t], a1 = b1[l * HFF_ + 256 + t];
    for (int i = 0; i < H_; ++i) {
      const float hv = hs[i];
      a0 = fmaf(hv, W1l[i * HFF_ + t], a0);
      a1 = fmaf(hv, W1l[i * HFF_ + 256 + t], a1);
    }
    hms[t] = fmaxf(a0, 0.f);
    hms[t + 256] = fmaxf(a1, 0.f);
    __syncthreads();
    float hn = hs[t] + b2[l * H_ + t];
    for (int jj = 0; jj < HFF_; ++jj)
      hn = fmaf(hms[jj], W2l[jj * H_ + t], hn);
    __syncthreads();
    hs[t] = hn;
    __syncthreads();
  }
  float cw = bout[t] + cb[k * D_ + t] + xhat[bf * D_ + t];
  for (int i = 0; i < H_; ++i) cw = fmaf(hs[i], Wout[i * D_ + t], cw);

  out[b * D_ + t] = cw;
  if (t < 2)
    out[B_ * D_ + t * B_ + b] = (float)codes[t * B_ + b];
  else if (t == 2)
    out[B_ * D_ + 2 * B_ + b] = (float)idx;
}

// ---------------------------------------------------------------------------
extern "C" void kernel_launch(void* const* d_in, const int* in_sizes, int n_in,
                              void* d_out, int out_size, void* d_ws, size_t ws_size,
                              hipStream_t stream) {
  const float* x    = (const float*)d_in[0];
  const float* xhat = (const float*)d_in[1];
  const int*   codes= (const int*)d_in[2];
  const float* cb   = (const float*)d_in[3];
  const float* Win  = (const float*)d_in[4];
  const float* bin  = (const float*)d_in[5];
  const float* Wcat = (const float*)d_in[6];
  const float* bcat = (const float*)d_in[7];
  const float* W1   = (const float*)d_in[8];
  const float* b1   = (const float*)d_in[9];
  const float* W2   = (const float*)d_in[10];
  const float* b2   = (const float*)d_in[11];
  const float* Wout = (const float*)d_in[12];
  const float* bout = (const float*)d_in[13];
  float* out = (float*)d_out;

  float* h0    = (float*)d_ws;                  // 65536 f
  float* u     = h0 + K_ * H_;                  // 65536 f
  float* v     = u + K_ * H_;                   // 262144 f
  float* dists = v + B_ * F_ * H_;              // 262144 f
  float* resc  = dists + B_ * F_ * K_;          // 1024 f
  int*   topi  = (int*)(resc + 1024);           // 1024 i
  int*   pad   = topi + 1024;                   // 128 pad (keeps 16B align)
  _Float16* w1f  = (_Float16*)(pad + 128);      // 2*H*HFF halves
  _Float16* w2f  = w1f + 2 * H_ * HFF_;
  _Float16* wof  = w2f + 2 * HFF_ * H_;

  k_h0<<<K_, 256, 0, stream>>>(cb, Win, bin, h0);
  k_uv<<<K_ + B_ * F_, 256, 0, stream>>>(h0, Wcat, bcat, xhat, u, v);
  k_wfrag16_all<<<2304, 256, 0, stream>>>(W1, W2, Wout, w1f, w2f, wof);

  k_main<<<B_ * F_ * (K_ / RT), 256, 0, stream>>>(u, v, w1f, b1, w2f, b2,
                                                  wof, bout, cb, xhat, x, dists);
  k_top8<<<B_, 256, 0, stream>>>(dists, topi);
  k_rescore<<<B_ * 8, 256, 0, stream>>>(u, v, W1, b1, W2, b2, Wout, bout, cb, xhat,
                                        x, topi, resc);
  k_final<<<B_, 256, 0, stream>>>(u, v, W1, b1, W2, b2, Wout, bout, cb, xhat,
                                  codes, topi, resc, out);
}

// Round 9
// 567.532 us; speedup vs baseline: 1.9168x; 1.0013x over previous
//
#include <hip/hip_runtime.h>
#include <hip/hip_bf16.h>

// Shapes (fixed): B=128, F=8, K=256, D=256, H=256, HFF=512, L=2, M_PREV=2
#define B_   128
#define F_   8
#define K_   256
#define D_   256
#define H_   256
#define HFF_ 512
#define RT   64   // candidates per block

typedef _Float16 half8  __attribute__((ext_vector_type(8)));  // f16x8 MFMA frag
typedef _Float16 half4v __attribute__((ext_vector_type(4)));
typedef float floatx4   __attribute__((ext_vector_type(4)));  // MFMA acc

#define MFMAH(a,b,c) __builtin_amdgcn_mfma_f32_16x16x32_f16(a,b,c,0,0,0)

// LDS strides (halves): 260 -> 130 dwords == 2 mod 32 (conflict-free b128);
// 132 -> 66 dwords == 2 mod 32. Total LDS 53248 B -> 3 blocks/CU.
#define HA_S  260
#define HMA_S 132

// ---------------------------------------------------------------------------
// R9: fused prep — one launch for (h0->u), v, and the fp16 weight shuffle.
// blocks [0,256): u[k] = (cb[k]@Win + bin)@Wcat_top   (h0 never hits HBM)
// blocks [256,1280): v[bf] = bcat + xhat[bf]@Wcat_bot
// blocks [1280,3584): weight fragment shuffle (W1/W2/Wout -> fp16 frag order)
__global__ void k_prep(const float* __restrict__ cb, const float* __restrict__ Win,
                       const float* __restrict__ bin, const float* __restrict__ Wcat,
                       const float* __restrict__ bcat, const float* __restrict__ xhat,
                       const float* __restrict__ W1, const float* __restrict__ W2,
                       const float* __restrict__ Wout,
                       float* __restrict__ u, float* __restrict__ v,
                       _Float16* __restrict__ w1f, _Float16* __restrict__ w2f,
                       _Float16* __restrict__ wof) {
  const int blk = blockIdx.x, t = threadIdx.x;
  if (blk < K_) {
    __shared__ float row[D_];
    __shared__ float h0row[H_];
    row[t] = cb[blk * D_ + t];
    __syncthreads();
    float acc = bin[t];
    #pragma unroll 4
    for (int i = 0; i < D_; ++i) acc = fmaf(row[i], Win[i * H_ + t], acc);
    h0row[t] = acc;
    __syncthreads();
    float acc2 = 0.f;
    #pragma unroll 4
    for (int i = 0; i < H_; ++i) acc2 = fmaf(h0row[i], Wcat[i * H_ + t], acc2);
    u[blk * H_ + t] = acc2;
  } else if (blk < K_ + B_ * F_) {
    __shared__ float row2[D_];
    const int bf = blk - K_;
    row2[t] = xhat[bf * D_ + t];
    __syncthreads();
    float acc = bcat[t];
    #pragma unroll 4
    for (int i = 0; i < D_; ++i) acc = fmaf(row2[i], Wcat[(H_ + i) * H_ + t], acc);
    v[bf * H_ + t] = acc;
  } else {
    const int e = (blk - (K_ + B_ * F_)) * 256 + t;
    const float* src; _Float16* dst; int N, NT, le;
    if (e < 262144) {
      const int layer = e >> 17; le = e & 131071;
      src = W1 + layer * (H_ * HFF_); dst = w1f + layer * (H_ * HFF_);
      N = HFF_; NT = 32;
    } else if (e < 524288) {
      const int e2 = e - 262144;
      const int layer = e2 >> 17; le = e2 & 131071;
      src = W2 + layer * (HFF_ * H_); dst = w2f + layer * (HFF_ * H_);
      N = H_; NT = 16;
    } else {
      le = e - 524288; src = Wout; dst = wof; N = D_; NT = 16;
    }
    const int jj = le & 7, lane = (le >> 3) & 63, r = le >> 9;
    const int ntile = r % NT, kstep = r / NT;
    const int row = kstep * 32 + (lane >> 4) * 8 + jj;
    const int colc = ntile * 16 + (lane & 15);
    dst[le] = (_Float16)src[row * N + colc];
  }
}

// ---------------------------------------------------------------------------
// MFMA main kernel: C' = W^T @ h^T, fp16 single-term, 64 candidates/block.
__global__ __launch_bounds__(256, 3) void k_main(
    const float* __restrict__ u, const float* __restrict__ v,
    const _Float16* __restrict__ w1f, const float* __restrict__ b1,
    const _Float16* __restrict__ w2f, const float* __restrict__ b2,
    const _Float16* __restrict__ woutf, const float* __restrict__ bout,
    const float* __restrict__ cb, const float* __restrict__ xhat,
    const float* __restrict__ x, float* __restrict__ dists) {
  __shared__ _Float16 hA[64][HA_S];    // 33280 B
  __shared__ _Float16 hmA[64][HMA_S];  // 16896 B
  __shared__ float x_s[D_], xh_s[D_];  // 2048 B
  __shared__ float dist_s[4][64];      // 1024 B

  const int t = threadIdx.x;
  const int blk = blockIdx.x;
  const int bf = blk >> 2, k0 = (blk & 3) << 6;
  const int b = bf >> 3, f = bf & 7;
  const int wave = t >> 6, lane = t & 63;
  const int col = lane & 15, quad = lane >> 4;
  const int lane8 = lane * 8;

  x_s[t]  = x[b * D_ + t];
  xh_s[t] = xhat[bf * D_ + t];

  // stage h = u + v -> fp16, packed 16B writes
  {
    const int r = t >> 2, c0 = (t & 3) * 64;
    const float* up = u + (k0 + r) * H_ + c0;
    const float* vp = v + bf * H_ + c0;
    #pragma unroll
    for (int j = 0; j < 64; j += 8) {
      float4 uA = *(const float4*)(up + j);
      float4 vA = *(const float4*)(vp + j);
      float4 uB = *(const float4*)(up + j + 4);
      float4 vB = *(const float4*)(vp + j + 4);
      half8 hv8;
      hv8[0] = (_Float16)(uA.x + vA.x); hv8[1] = (_Float16)(uA.y + vA.y);
      hv8[2] = (_Float16)(uA.z + vA.z); hv8[3] = (_Float16)(uA.w + vA.w);
      hv8[4] = (_Float16)(uB.x + vB.x); hv8[5] = (_Float16)(uB.y + vB.y);
      hv8[6] = (_Float16)(uB.z + vB.z); hv8[7] = (_Float16)(uB.w + vB.w);
      *(half8*)&hA[r][c0 + j] = hv8;
    }
  }
  __syncthreads();

  const floatx4 zero4 = {0.f, 0.f, 0.f, 0.f};

  #pragma unroll 1
  for (int l = 0; l < 2; ++l) {
    const _Float16* w1_l = w1f + l * (H_ * HFF_);
    const _Float16* w2_l = w2f + l * (HFF_ * H_);
    const float* b1l = b1 + l * HFF_;
    const float* b2l = b2 + l * H_;

    floatx4 acc2[4][4];   // [out-feature tile][candidate-row tile]
    #pragma unroll
    for (int mt = 0; mt < 4; ++mt)
      #pragma unroll
      for (int nt = 0; nt < 4; ++nt) acc2[mt][nt] = zero4;

    #pragma unroll 1
    for (int ch = 0; ch < 4; ++ch) {
      // ---- GEMM1': hm' = relu(W1[:,chunk]^T @ h^T + b1) ----
      floatx4 acc1[2][4];
      #pragma unroll
      for (int mt = 0; mt < 2; ++mt)
        #pragma unroll
        for (int nt = 0; nt < 4; ++nt) acc1[mt][nt] = zero4;

      const _Float16* w1_b = w1_l + (ch * 8 + wave * 2) * 512 + lane8;

      // R9: unroll 4 — deeper in-flight L2 weight loads (watch WRITE_SIZE)
      #pragma unroll 4
      for (int ks = 0; ks < 8; ++ks) {
        half8 b0 = *(const half8*)&hA[col][ks * 32 + quad * 8];
        half8 b1v = *(const half8*)&hA[16 + col][ks * 32 + quad * 8];
        half8 b2v = *(const half8*)&hA[32 + col][ks * 32 + quad * 8];
        half8 b3v = *(const half8*)&hA[48 + col][ks * 32 + quad * 8];
        const int ko = ks * 32 * 512;
        #pragma unroll
        for (int mt = 0; mt < 2; ++mt) {
          half8 aw = *(const half8*)(w1_b + ko + mt * 512);
          acc1[mt][0] = MFMAH(aw, b0, acc1[mt][0]);
          acc1[mt][1] = MFMAH(aw, b1v, acc1[mt][1]);
          acc1[mt][2] = MFMAH(aw, b2v, acc1[mt][2]);
          acc1[mt][3] = MFMAH(aw, b3v, acc1[mt][3]);
        }
      }
      // bias + relu -> fp16, packed 8B stores (4 consecutive features/lane)
      #pragma unroll
      for (int mt = 0; mt < 2; ++mt) {
        const int floc = (wave * 2 + mt) * 16 + quad * 4;
        float4 bb = *(const float4*)&b1l[ch * 128 + floc];
        #pragma unroll
        for (int nt = 0; nt < 4; ++nt) {
          const int row = nt * 16 + col;
          half4v nh;
          #pragma unroll
          for (int p = 0; p < 4; ++p)
            nh[p] = (_Float16)fmaxf(acc1[mt][nt][p] + ((const float*)&bb)[p], 0.f);
          *(half4v*)&hmA[row][floc] = nh;
        }
      }
      __syncthreads();

      // ---- GEMM2': acc2 += W2[chunk,:]^T @ hm'^T ----
      const _Float16* w2_b = w2_l + (ch * 64 + wave * 4) * 512 + lane8;
      #pragma unroll 2
      for (int ks = 0; ks < 4; ++ks) {
        half8 b0 = *(const half8*)&hmA[col][ks * 32 + quad * 8];
        half8 b1v = *(const half8*)&hmA[16 + col][ks * 32 + quad * 8];
        half8 b2v = *(const half8*)&hmA[32 + col][ks * 32 + quad * 8];
        half8 b3v = *(const half8*)&hmA[48 + col][ks * 32 + quad * 8];
        const int ko = ks * 16 * 512;
        #pragma unroll
        for (int mt = 0; mt < 4; ++mt) {
          half8 aw = *(const half8*)(w2_b + ko + mt * 512);
          acc2[mt][0] = MFMAH(aw, b0, acc2[mt][0]);
          acc2[mt][1] = MFMAH(aw, b1v, acc2[mt][1]);
          acc2[mt][2] = MFMAH(aw, b2v, acc2[mt][2]);
          acc2[mt][3] = MFMAH(aw, b3v, acc2[mt][3]);
        }
      }
      __syncthreads();
    }

    // ---- residual: h += acc2 + b2, packed 8B read/modify/write ----
    #pragma unroll
    for (int mt = 0; mt < 4; ++mt) {
      const int feat0 = (wave * 4 + mt) * 16 + quad * 4;
      float4 bb = *(const float4*)&b2l[feat0];
      #pragma unroll
      for (int nt = 0; nt < 4; ++nt) {
        const int row = nt * 16 + col;
        half4v oh = *(half4v*)&hA[row][feat0];
        half4v nh;
        #pragma unroll
        for (int p = 0; p < 4; ++p)
          nh[p] = (_Float16)((float)oh[p] + acc2[mt][nt][p] + ((const float*)&bb)[p]);
        *(half4v*)&hA[row][feat0] = nh;
      }
    }
    __syncthreads();
  }

  // ---- GEMM3': cw' = Wout^T @ h^T (+bout+cb+xhat), then distance ----
  floatx4 acc3[4][4];
  #pragma unroll
  for (int mt = 0; mt < 4; ++mt)
    #pragma unroll
    for (int nt = 0; nt < 4; ++nt) acc3[mt][nt] = zero4;

  const _Float16* wo_b = woutf + (wave * 4) * 512 + lane8;
  #pragma unroll 2
  for (int ks = 0; ks < 8; ++ks) {
    half8 b0 = *(const half8*)&hA[col][ks * 32 + quad * 8];
    half8 b1v = *(const half8*)&hA[16 + col][ks * 32 + quad * 8];
    half8 b2v = *(const half8*)&hA[32 + col][ks * 32 + quad * 8];
    half8 b3v = *(const half8*)&hA[48 + col][ks * 32 + quad * 8];
    const int ko = ks * 16 * 512;
    #pragma unroll
    for (int mt = 0; mt < 4; ++mt) {
      half8 aw = *(const half8*)(wo_b + ko + mt * 512);
      acc3[mt][0] = MFMAH(aw, b0, acc3[mt][0]);
      acc3[mt][1] = MFMAH(aw, b1v, acc3[mt][1]);
      acc3[mt][2] = MFMAH(aw, b2v, acc3[mt][2]);
      acc3[mt][3] = MFMAH(aw, b3v, acc3[mt][3]);
    }
  }

  float s[4] = {0.f, 0.f, 0.f, 0.f};
  #pragma unroll
  for (int mt = 0; mt < 4; ++mt) {
    const int d0 = (wave * 4 + mt) * 16 + quad * 4;
    float4 bo = *(const float4*)&bout[d0];
    float4 xv = *(const float4*)&x_s[d0];
    float4 xh4 = *(const float4*)&xh_s[d0];
    #pragma unroll
    for (int nt = 0; nt < 4; ++nt) {
      float4 cbv = *(const float4*)&cb[(k0 + nt * 16 + col) * D_ + d0];
      #pragma unroll
      for (int p = 0; p < 4; ++p) {
        float base = ((const float*)&bo)[p] + ((const float*)&xh4)[p];
        float xx = ((const float*)&xv)[p];
        float cw = acc3[mt][nt][p] + base + ((const float*)&cbv)[p];
        s[nt] += cw * (cw - 2.f * xx);   // -||x||^2 const: argmin-invariant
      }
    }
  }
  #pragma unroll
  for (int nt = 0; nt < 4; ++nt) {
    s[nt] += __shfl_xor(s[nt], 16, 64);
    s[nt] += __shfl_xor(s[nt], 32, 64);
  }
  if (quad == 0) {
    #pragma unroll
    for (int nt = 0; nt < 4; ++nt)
      dist_s[wave][nt * 16 + col] = s[nt];
  }
  __syncthreads();
  if (t < 64) {
    float d = dist_s[0][t] + dist_s[1][t] + dist_s[2][t] + dist_s[3][t];
    dists[b * (F_ * K_) + f * K_ + k0 + t] = d;
  }
}

// ---------------------------------------------------------------------------
// Top-8 candidates per b from approx dists (iterative selection).
__global__ void k_top8(const float* __restrict__ dists, int* __restrict__ topi) {
  __shared__ float ds[F_ * K_];
  __shared__ float bv[256];
  __shared__ int bi_s[256];
  const int b = blockIdx.x, t = threadIdx.x;
  for (int j = t; j < F_ * K_; j += 256) ds[j] = dists[b * (F_ * K_) + j];
  __syncthreads();
  for (int pass = 0; pass < 8; ++pass) {
    float best = 3.4e38f; int bi = 0;
    for (int j = t; j < F_ * K_; j += 256) {
      const float dv = ds[j];
      if (dv < best) { best = dv; bi = j; }
    }
    bv[t] = best; bi_s[t] = bi;
    __syncthreads();
    for (int s = 128; s > 0; s >>= 1) {
      if (t < s) {
        const float ov = bv[t + s]; const int oi = bi_s[t + s];
        if (ov < bv[t] || (ov == bv[t] && oi < bi_s[t])) { bv[t] = ov; bi_s[t] = oi; }
      }
      __syncthreads();
    }
    if (t == 0) { topi[b * 8 + pass] = bi_s[0]; ds[bi_s[0]] = 3.4e38f; }
    __syncthreads();
  }
}

// ---------------------------------------------------------------------------
// Exact fp32 rescore of one candidate row per block (same math as R2 pass).
__global__ void k_rescore(const float* __restrict__ u, const float* __restrict__ v,
                          const float* __restrict__ W1, const float* __restrict__ b1,
                          const float* __restrict__ W2, const float* __restrict__ b2,
                          const float* __restrict__ Wout, const float* __restrict__ bout,
                          const float* __restrict__ cb, const float* __restrict__ xhat,
                          const float* __restrict__ x, const int* __restrict__ topi,
                          float* __restrict__ resc) {
  __shared__ float hs[H_];
  __shared__ float hms[HFF_];
  __shared__ float red[256];
  const int bc = blockIdx.x, t = threadIdx.x;
  const int b = bc >> 3;
  const int idx = topi[bc];
  const int f = idx >> 8, k = idx & 255;
  const int bf = b * F_ + f;

  hs[t] = u[k * H_ + t] + v[bf * H_ + t];
  __syncthreads();
  for (int l = 0; l < 2; ++l) {
    const float* W1l = W1 + l * (H_ * HFF_);
    const float* W2l = W2 + l * (HFF_ * H_);
    float a0 = b1[l * HFF_ + t], a1 = b1[l * HFF_ + 256 + t];
    for (int i = 0; i < H_; ++i) {
      const float hv = hs[i];
      a0 = fmaf(hv, W1l[i * HFF_ + t], a0);
      a1 = fmaf(hv, W1l[i * HFF_ + 256 + t], a1);
    }
    hms[t] = fmaxf(a0, 0.f);
    hms[t + 256] = fmaxf(a1, 0.f);
    __syncthreads();
    float hn = hs[t] + b2[l * H_ + t];
    for (int jj = 0; jj < HFF_; ++jj)
      hn = fmaf(hms[jj], W2l[jj * H_ + t], hn);
    __syncthreads();
    hs[t] = hn;
    __syncthreads();
  }
  float cw = bout[t] + cb[k * D_ + t] + xhat[bf * D_ + t];
  for (int i = 0; i < H_; ++i) cw = fmaf(hs[i], Wout[i * D_ + t], cw);
  red[t] = cw * (cw - 2.f * x[b * D_ + t]);
  __syncthreads();
  for (int s = 128; s > 0; s >>= 1) {
    if (t < s) red[t] += red[t + s];
    __syncthreads();
  }
  if (t == 0) resc[bc] = red[0];
}

// ---------------------------------------------------------------------------
// Pick exact argmin among 8 rescored candidates; recompute winner; write out.
__global__ void k_final(const float* __restrict__ u, const float* __restrict__ v,
                        const float* __restrict__ W1, const float* __restrict__ b1,
                        const float* __restrict__ W2, const float* __restrict__ b2,
                        const float* __restrict__ Wout, const float* __restrict__ bout,
                        const float* __restrict__ cb, const float* __restrict__ xhat,
                        const int* __restrict__ codes, const int* __restrict__ topi,
                        const float* __restrict__ resc, float* __restrict__ out) {
  __shared__ float hs[H_];
  __shared__ float hms[HFF_];
  __shared__ int idx_sh;
  const int b = blockIdx.x, t = threadIdx.x;
  if (t == 0) {
    float bd = 3.4e38f; int bidx = 1 << 30;
    for (int c = 0; c < 8; ++c) {
      const float d = resc[b * 8 + c];
      const int ix = topi[b * 8 + c];
      if (d < bd || (d == bd && ix < bidx)) { bd = d; bidx = ix; }
    }
    idx_sh = bidx;
  }
  __syncthreads();
  const int idx = idx_sh;
  const int f = idx >> 8, k = idx & 255;
  const int bf = b * F_ + f;

  hs[t] = u[k * H_ + t] + v[bf * H_ + t];
  __syncthreads();
  for (int l = 0; l < 2; ++l) {
    const float* W1l = W1 + l * (H_ * HFF_);
    const float* W2l = W2 + l * (HFF_ * H_);
    float a0 = b1[l * HFF_ + t], a1 = b1[l * HFF_ + 256 + t];
    for (int i = 0; i < H_; ++i) {
      const float hv = hs[i];
      a0 = fmaf(hv, W1l[i * HFF_ + t], a0);
      a1 = fmaf(hv, W1l[i * HFF_ + 256 + t], a1);
    }
    hms[t] = fmaxf(a0, 0.f);
    hms[t + 256] = fmaxf(a1, 0.f);
    __syncthreads();
    float hn = hs[t] + b2[l * H_ + t];
    for (int jj = 0; jj < HFF_; ++jj)
      hn = fmaf(hms[jj], W2l[jj * H_ + t], hn);
    __syncthreads();
    hs[t] = hn;
    __syncthreads();
  }
  float cw = bout[t] + cb[k * D_ + t] + xhat[bf * D_ + t];
  for (int i = 0; i < H_; ++i) cw = fmaf(hs[i], Wout[i * D_ + t], cw);

  out[b * D_ + t] = cw;
  if (t < 2)
    out[B_ * D_ + t * B_ + b] = (float)codes[t * B_ + b];
  else if (t == 2)
    out[B_ * D_ + 2 * B_ + b] = (float)idx;
}

// ---------------------------------------------------------------------------
extern "C" void kernel_launch(void* const* d_in, const int* in_sizes, int n_in,
                              void* d_out, int out_size, void* d_ws, size_t ws_size,
                              hipStream_t stream) {
  const float* x    = (const float*)d_in[0];
  const float* xhat = (const float*)d_in[1];
  const int*   codes= (const int*)d_in[2];
  const float* cb   = (const float*)d_in[3];
  const float* Win  = (const float*)d_in[4];
  const float* bin  = (const float*)d_in[5];
  const float* Wcat = (const float*)d_in[6];
  const float* bcat = (const float*)d_in[7];
  const float* W1   = (const float*)d_in[8];
  const float* b1   = (const float*)d_in[9];
  const float* W2   = (const float*)d_in[10];
  const float* b2   = (const float*)d_in[11];
  const float* Wout = (const float*)d_in[12];
  const float* bout = (const float*)d_in[13];
  float* out = (float*)d_out;

  float* u     = (float*)d_ws;                  // 65536 f (h0 eliminated)
  float* v     = u + K_ * H_;                   // 262144 f
  float* dists = v + B_ * F_ * H_;              // 262144 f
  float* resc  = dists + B_ * F_ * K_;          // 1024 f
  int*   topi  = (int*)(resc + 1024);           // 1024 i
  int*   pad   = topi + 1024;                   // 128 pad (keeps 16B align)
  _Float16* w1f  = (_Float16*)(pad + 128);      // 2*H*HFF halves
  _Float16* w2f  = w1f + 2 * H_ * HFF_;
  _Float16* wof  = w2f + 2 * HFF_ * H_;

  k_prep<<<K_ + B_ * F_ + 2304, 256, 0, stream>>>(cb, Win, bin, Wcat, bcat, xhat,
                                                  W1, W2, Wout, u, v, w1f, w2f, wof);

  k_main<<<B_ * F_ * (K_ / RT), 256, 0, stream>>>(u, v, w1f, b1, w2f, b2,
                                                  wof, bout, cb, xhat, x, dists);
  k_top8<<<B_, 256, 0, stream>>>(dists, topi);
  k_rescore<<<B_ * 8, 256, 0, stream>>>(u, v, W1, b1, W2, b2, Wout, bout, cb, xhat,
                                        x, topi, resc);
  k_final<<<B_, 256, 0, stream>>>(u, v, W1, b1, W2, b2, Wout, bout, cb, xhat,
                                  codes, topi, resc, out);
}